// Round 13
// baseline (581.855 us; speedup 1.0000x reference)
//
#include <hip/hip_runtime.h>
#include <cstdint>
#include <cstddef>

namespace {

typedef unsigned short ushort_t;
typedef __bf16 bf16x8 __attribute__((ext_vector_type(8)));
typedef float  f32x4  __attribute__((ext_vector_type(4)));

constexpr int B_ = 4;
constexpr int N0 = 4096;   // vertices per batch
constexpr int N1 = 1024;   // after pool1
constexpr int N2 = 256;    // after pool2

// ----------------------------------------------------- bf16 split utils ----
__device__ __forceinline__ ushort_t f2bf_rne(float x) {
  uint32_t b = __float_as_uint(x);
  b += 0x7FFFu + ((b >> 16) & 1u);
  return (ushort_t)(b >> 16);
}
__device__ __forceinline__ float bf2f(ushort_t h) {
  return __uint_as_float(((uint32_t)h) << 16);
}
__device__ __forceinline__ void split_store(float x, ushort_t* hi, ushort_t* lo,
                                            size_t i) {
  const ushort_t h = f2bf_rne(x);
  hi[i] = h;
  lo[i] = f2bf_rne(x - bf2f(h));
}

// ------------------- fused prep: weight split/transpose + vp1/vp2 gather ---
__global__ void prep_kernel(
    const float* __restrict__ w1, const float* __restrict__ w2,
    const float* __restrict__ w3, const float* __restrict__ w4,
    const float* __restrict__ cw1, const float* __restrict__ cw2,
    const float* __restrict__ vertices,
    const int* __restrict__ sidx1, const int* __restrict__ sidx2,
    ushort_t* __restrict__ w1th, ushort_t* __restrict__ w1tl,
    ushort_t* __restrict__ w2th, ushort_t* __restrict__ w2tl,
    ushort_t* __restrict__ w3th, ushort_t* __restrict__ w3tl,
    ushort_t* __restrict__ w4th, ushort_t* __restrict__ w4tl,
    ushort_t* __restrict__ w1h, ushort_t* __restrict__ w1l,
    ushort_t* __restrict__ w2h, ushort_t* __restrict__ w2l,
    float* __restrict__ vp1, float* __restrict__ vp2)
{
  const int i = blockIdx.x * blockDim.x + threadIdx.x;
  if (i < 32768) {                       // w1: K=128, N=256
    const int j = i, k = j % 128, n = j / 128;
    split_store(w1[(size_t)k * 256 + n], w1th, w1tl, (size_t)n * 128 + k);
  } else if (i < 98304) {                // w2: K=128, N=512
    const int j = i - 32768, k = j % 128, n = j / 128;
    split_store(w2[(size_t)k * 512 + n], w2th, w2tl, (size_t)n * 128 + k);
  } else if (i < 229376) {               // w3: K=256, N=512
    const int j = i - 98304, k = j % 256, n = j / 256;
    split_store(w3[(size_t)k * 512 + n], w3th, w3tl, (size_t)n * 256 + k);
  } else if (i < 491520) {               // w4: K=256, N=1024
    const int j = i - 229376, k = j % 256, n = j / 256;
    split_store(w4[(size_t)k * 1024 + n], w4th, w4tl, (size_t)n * 256 + k);
  } else if (i < 1409024) {              // cw1: already (N,K)
    const int j = i - 491520;
    split_store(cw1[j], w1h, w1l, j);
  } else if (i < 1671168) {              // cw2
    const int j = i - 1409024;
    split_store(cw2[j], w2h, w2l, j);
  } else if (i < 1683456) {              // vp1 = vertices[:, sidx1, :]
    const int j = i - 1671168;
    const int c = j % 3, q = (j / 3) % N1, b = j / (3 * N1);
    vp1[j] = vertices[((size_t)b * N0 + sidx1[q]) * 3 + c];
  } else if (i < 1686528) {              // vp2 = vertices[:, sidx1[sidx2], :]
    const int j = i - 1683456;
    const int c = j % 3, q = (j / 3) % N2, b = j / (3 * N2);
    vp2[j] = vertices[((size_t)b * N0 + sidx1[sidx2[q]]) * 3 + c];
  }
}

// ------------------------------------------------- wave-cooperative KNN ----
__device__ __forceinline__ void bitonic_sort64(float& sd, int& si, int lane) {
#pragma unroll
  for (int kk = 2; kk <= 64; kk <<= 1) {
#pragma unroll
    for (int j = kk >> 1; j > 0; j >>= 1) {
      const float od = __shfl_xor(sd, j);
      const int   oi = __shfl_xor(si, j);
      const bool less    = (sd < od) || (sd == od && si < oi);
      const bool wantMin = ((lane & j) == 0) == ((lane & kk) == 0);
      if (wantMin != less) { sd = od; si = oi; }
    }
  }
}

__device__ __forceinline__ void knn_flush(float& ld, int& li, float& tau,
                                          int cnt, const float* bufd,
                                          const int* bufi, int lane, int Km1) {
  float sd = (lane < cnt) ? bufd[lane] : INFINITY;
  int   si = (lane < cnt) ? bufi[lane] : 0x7fffffff;
  bitonic_sort64(sd, si, lane);
  const float rd = __shfl(sd, 63 - lane);
  const int   ri = __shfl(si, 63 - lane);
  const bool keep = (ld < rd) || (ld == rd && li < ri);
  float md = keep ? ld : rd;
  int   mi = keep ? li : ri;
#pragma unroll
  for (int j = 32; j > 0; j >>= 1) {
    const float od = __shfl_xor(md, j);
    const int   oi = __shfl_xor(mi, j);
    const bool less    = (md < od) || (md == od && mi < oi);
    const bool wantMin = ((lane & j) == 0);
    if (wantMin != less) { md = od; mi = oi; }
  }
  ld = md; li = mi;
  tau = __shfl(ld, Km1);
}

// All 3 KNN levels in ONE dispatch (proven round-12 config: 8 waves/block).
__launch_bounds__(512)
__global__ void knn_mega_kernel(const float* __restrict__ verts,
                                const float* __restrict__ vp1,
                                const float* __restrict__ vp2,
                                int* __restrict__ nb1,
                                int* __restrict__ nb2,
                                int* __restrict__ nb3)
{
  constexpr int K = 32, TILE = 2048;
  __shared__ float4 sp[TILE];
  __shared__ float sbd[8][64];
  __shared__ int   sbi[8][64];

  int bx = blockIdx.x;
  const float* pts; int Q, C; int* out;
  if (bx < 2048)      { pts = verts; Q = N0; C = N0; out = nb1; }
  else if (bx < 2560) { pts = vp1;   Q = N1; C = N1; out = nb2; bx -= 2048; }
  else                { pts = vp2;   Q = N2; C = N2; out = nb3; bx -= 2560; }
  const int bpb = Q / 8;
  const int b  = bx / bpb;
  const int lane = threadIdx.x & 63;
  const int wid  = threadIdx.x >> 6;
  const int q    = (bx % bpb) * 8 + wid;
  const int self = q;
  const float* pb = pts + (size_t)b * C * 3;
  const float qx = pb[self * 3 + 0];
  const float qy = pb[self * 3 + 1];
  const float qz = pb[self * 3 + 2];
  const float q2   = qx * qx + qy * qy + qz * qz;
  const float m2qx = -2.0f * qx, m2qy = -2.0f * qy, m2qz = -2.0f * qz;

  float ld = INFINITY; int li = 0x7fffffff;
  float tau = INFINITY;
  int cnt = 0;
  float* bufd = sbd[wid];
  int*   bufi = sbi[wid];

  auto append = [&](unsigned long long m, bool cand, float d, int ci) {
    const int c = __popcll(m);
    if (cnt + c > 64) {
      knn_flush(ld, li, tau, cnt, bufd, bufi, lane, K - 1);
      cnt = 0;
    }
    const int prefix = __popcll(m & ((1ull << lane) - 1ull));
    if (cand) { bufd[cnt + prefix] = d; bufi[cnt + prefix] = ci; }
    cnt += c;
  };

  for (int t0 = 0; t0 < C; t0 += TILE) {
    const int nt = (C - t0 < TILE) ? (C - t0) : TILE;
    __syncthreads();
    for (int i = threadIdx.x; i < nt; i += 512) {
      const float x = pb[(t0 + i) * 3 + 0];
      const float y = pb[(t0 + i) * 3 + 1];
      const float z = pb[(t0 + i) * 3 + 2];
      sp[i] = make_float4(x, y, z, x * x + y * y + z * z);
    }
    __syncthreads();
    int base = 0;
    if (t0 == 0) {
      const float4 p = sp[lane];
      const float d = fmaf(m2qx, p.x, fmaf(m2qy, p.y, fmaf(m2qz, p.z, p.w + q2)));
      const bool valid = (lane != self);
      float sd = valid ? d : INFINITY;
      int   si = valid ? lane : 0x7fffffff;
      bitonic_sort64(sd, si, lane);
      ld = sd; li = si;
      tau = __shfl(ld, K - 1);
      base = 64;
    }
    for (; base + 128 <= nt; base += 128) {
      const int ci0 = t0 + base + lane;
      const int ci1 = ci0 + 64;
      const float4 p0 = sp[base + lane];
      const float4 p1 = sp[base + 64 + lane];
      const float d0 = fmaf(m2qx, p0.x, fmaf(m2qy, p0.y, fmaf(m2qz, p0.z, p0.w + q2)));
      const float d1 = fmaf(m2qx, p1.x, fmaf(m2qy, p1.y, fmaf(m2qz, p1.z, p1.w + q2)));
      const bool c0 = (ci0 != self) && (d0 < tau);
      const bool c1 = (ci1 != self) && (d1 < tau);
      const unsigned long long m0 = __ballot(c0);
      const unsigned long long m1 = __ballot(c1);
      if (m0) append(m0, c0, d0, ci0);
      if (m1) append(m1, c1, d1, ci1);
    }
    if (base < nt) {
      const int ci = t0 + base + lane;
      const float4 p = sp[base + lane];
      const float d = fmaf(m2qx, p.x, fmaf(m2qy, p.y, fmaf(m2qz, p.z, p.w + q2)));
      const bool c = (ci != self) && (d < tau);
      const unsigned long long m = __ballot(c);
      if (m) append(m, c, d, ci);
    }
  }
  if (cnt > 0) knn_flush(ld, li, tau, cnt, bufd, bufi, lane, K - 1);
  if (lane < K) out[((size_t)b * Q + q) * K + lane] = li;
}

// -------------------------------------------- dual-level wave argmin -------
__launch_bounds__(256)
__global__ void nearest_dual_kernel(const float* __restrict__ qpts, // (B*N0,3)
                                    const float* __restrict__ cpts1,
                                    const float* __restrict__ cpts2,
                                    int* __restrict__ out1,
                                    int* __restrict__ out2)
{
  __shared__ float4 sp[1024];
  const int lvl = blockIdx.y;
  const int C = lvl ? N2 : N1;
  const float* cpts = lvl ? cpts2 : cpts1;
  int* out = lvl ? out2 : out1;
  const int lane = threadIdx.x & 63;
  const int wid  = threadIdx.x >> 6;
  const int q    = blockIdx.x * 4 + wid;
  const int b    = q >> 12;
  const float qx = qpts[(size_t)q * 3 + 0];
  const float qy = qpts[(size_t)q * 3 + 1];
  const float qz = qpts[(size_t)q * 3 + 2];
  const float q2   = qx * qx + qy * qy + qz * qz;
  const float m2qx = -2.0f * qx, m2qy = -2.0f * qy, m2qz = -2.0f * qz;
  const float* pb = cpts + (size_t)b * C * 3;

  for (int i = threadIdx.x; i < C; i += 256) {
    const float x = pb[i * 3 + 0];
    const float y = pb[i * 3 + 1];
    const float z = pb[i * 3 + 2];
    sp[i] = make_float4(x, y, z, x * x + y * y + z * z);
  }
  __syncthreads();
  float best = INFINITY; int bi = 0x7fffffff;
  for (int base = 0; base < C; base += 64) {
    const float4 p = sp[base + lane];
    const float d = fmaf(m2qx, p.x, fmaf(m2qy, p.y, fmaf(m2qz, p.z, p.w + q2)));
    if (d < best) { best = d; bi = base + lane; }
  }
#pragma unroll
  for (int j = 1; j < 64; j <<= 1) {
    const float od = __shfl_xor(best, j);
    const int   oi = __shfl_xor(bi, j);
    if (od < best || (od == best && oi < bi)) { best = od; bi = oi; }
  }
  if (lane == 0) out[q] = bi;
}

// -------------------------------------------------------- conv_surface -----
__global__ void conv_surface_kernel(const float* __restrict__ verts,
                                    const int*   __restrict__ nb,
                                    const float* __restrict__ dir,
                                    int V, int C,
                                    ushort_t* __restrict__ outH,
                                    ushort_t* __restrict__ outL) {
  __shared__ float ux[32], uy[32], uz[32];
  const int bv = blockIdx.x;
  const int b = bv / V;
  const int v = bv - b * V;
  const float* vb = verts + (size_t)b * V * 3;
  if (threadIdx.x < 32) {
    const float cx = vb[v * 3 + 0], cy = vb[v * 3 + 1], cz = vb[v * 3 + 2];
    const int nidx = nb[(size_t)bv * 32 + threadIdx.x];
    const float dx = vb[nidx * 3 + 0] - cx;
    const float dy = vb[nidx * 3 + 1] - cy;
    const float dz = vb[nidx * 3 + 2] - cz;
    const float rn = 1.0f / fmaxf(sqrtf(dx * dx + dy * dy + dz * dz), 1e-12f);
    ux[threadIdx.x] = dx * rn; uy[threadIdx.x] = dy * rn; uz[threadIdx.x] = dz * rn;
  }
  __syncthreads();
  const int o = threadIdx.x;
  float d0 = dir[o], d1 = dir[C + o], d2 = dir[2 * C + o];
  const float rn = 1.0f / fmaxf(sqrtf(d0 * d0 + d1 * d1 + d2 * d2), 1e-12f);
  d0 *= rn; d1 *= rn; d2 *= rn;
  float m = -INFINITY;
#pragma unroll
  for (int n = 0; n < 32; ++n) {
    const float t = fmaxf(0.0f, fmaf(d2, uz[n], fmaf(d1, uy[n], d0 * ux[n])));
    m = fmaxf(m, t);
  }
  split_store(fmaxf(0.0f, m), outH, outL, (size_t)bv * C + o);
}

// -------------------------------------------------------- conv_combine -----
__global__ void conv_combine_kernel(const float* __restrict__ f,    // (B,V,2C)
                                    const int*   __restrict__ nb,
                                    const float* __restrict__ dir,
                                    const float* __restrict__ verts,
                                    int V, int C, int relu,
                                    ushort_t* __restrict__ outH,
                                    ushort_t* __restrict__ outL) {
  __shared__ float ux[32], uy[32], uz[32];
  __shared__ int snb[32];
  const int bv = blockIdx.x;
  const int b = bv / V;
  const int v = bv - b * V;
  const float* vb = verts + (size_t)b * V * 3;
  if (threadIdx.x < 32) {
    const float cx = vb[v * 3 + 0], cy = vb[v * 3 + 1], cz = vb[v * 3 + 2];
    const int nidx = nb[(size_t)bv * 32 + threadIdx.x];
    snb[threadIdx.x] = nidx;
    const float dx = vb[nidx * 3 + 0] - cx;
    const float dy = vb[nidx * 3 + 1] - cy;
    const float dz = vb[nidx * 3 + 2] - cz;
    const float rn = 1.0f / fmaxf(sqrtf(dx * dx + dy * dy + dz * dz), 1e-12f);
    ux[threadIdx.x] = dx * rn; uy[threadIdx.x] = dy * rn; uz[threadIdx.x] = dz * rn;
  }
  __syncthreads();
  const int o = threadIdx.x;
  float d0 = dir[o], d1 = dir[C + o], d2 = dir[2 * C + o];
  const float rn = 1.0f / fmaxf(sqrtf(d0 * d0 + d1 * d1 + d2 * d2), 1e-12f);
  d0 *= rn; d1 *= rn; d2 *= rn;
  const float* fb = f + (size_t)b * V * 2 * C;
  float m = -INFINITY;
#pragma unroll 8
  for (int n = 0; n < 32; ++n) {
    const float t = fmaxf(0.0f, fmaf(d2, uz[n], fmaf(d1, uy[n], d0 * ux[n])));
    const float s = fb[(size_t)snb[n] * 2 * C + C + o];
    m = fmaxf(m, t * s);
  }
  float r = fb[(size_t)v * 2 * C + o] + m;
  if (relu) r = fmaxf(r, 0.0f);
  split_store(r, outH, outL, (size_t)bv * C + o);
}

// ---------------------------------------------------------------- pool -----
__global__ void pool_kernel(const ushort_t* __restrict__ fmH,
                            const ushort_t* __restrict__ fmL,
                            const int*   __restrict__ nb,   // (B, Vsrc, 32)
                            const int*   __restrict__ sidx, // (Q,)
                            int Q, int Vsrc, int C,
                            ushort_t* __restrict__ outH,
                            ushort_t* __restrict__ outL) {
  const int i = blockIdx.x * blockDim.x + threadIdx.x;
  if (i >= B_ * Q * C) return;
  const int c = i % C;
  const int q = (i / C) % Q;
  const int b = i / (C * Q);
  const int* nn = nb + ((size_t)b * Vsrc + sidx[q]) * 32;
  const size_t fb = (size_t)b * Vsrc * C;
  float m = -INFINITY;
#pragma unroll
  for (int t = 0; t < 4; ++t) {
    const size_t idx = fb + (size_t)nn[t] * C + c;
    m = fmaxf(m, bf2f(fmH[idx]) + bf2f(fmL[idx]));
  }
  split_store(m, outH, outL, (size_t)i);
}

// grid = B_*8 blocks of 256 thr: 64 channels x 4 v-slices per block
__global__ void global_max_kernel(const ushort_t* __restrict__ fmH,
                                  const ushort_t* __restrict__ fmL,
                                  ushort_t* __restrict__ outH,
                                  ushort_t* __restrict__ outL) {
  __shared__ float red[4][64];
  const int t = threadIdx.x;
  const int cl = t & 63, slice = t >> 6;
  const int c = (blockIdx.x & 7) * 64 + cl;
  const int b = blockIdx.x >> 3;
  const size_t base = (size_t)b * 256 * 512 + c;
  float m = -INFINITY;
  for (int v = slice; v < 256; v += 4) {
    const size_t idx = base + (size_t)v * 512;
    m = fmaxf(m, bf2f(fmH[idx]) + bf2f(fmL[idx]));
  }
  red[slice][cl] = m;
  __syncthreads();
  if (slice == 0) {
    m = fmaxf(fmaxf(red[0][cl], red[1][cl]), fmaxf(red[2][cl], red[3][cl]));
    split_store(m, outH, outL, (size_t)b * 512 + c);
  }
}

// ------------------------------------------- split-bf16 MFMA GEMM ----------
// Round-8 staging structure + two changes this round:
//  * LDT 40 -> 36: LDS 40960 -> 36864 B/block => 4 blocks/CU (was 3).
//    Frag-read start banks 18*ml mod 32 cover all even banks exactly twice
//    -> 2-way aliasing everywhere, free (m136).
//  * Explicit next-K-slice prefetch issued before the MFMA section so the
//    global-load latency overlaps the 48 MFMAs instead of the loop boundary.
constexpr int LDT = 36;  // LDS row stride in ushorts (32 + 4 pad)

template<bool FUSE, bool SPLITOUT, bool RELU>
__launch_bounds__(256)
__global__ void mfma_gemm_kernel(
    const ushort_t* __restrict__ Ahi, const ushort_t* __restrict__ Alo,
    const ushort_t* __restrict__ f0h, const ushort_t* __restrict__ f0l,
    const ushort_t* __restrict__ f1h, const ushort_t* __restrict__ f1l,
    const ushort_t* __restrict__ f2h, const ushort_t* __restrict__ f2l,
    const ushort_t* __restrict__ f3h, const ushort_t* __restrict__ f3l,
    const ushort_t* __restrict__ f4h, const ushort_t* __restrict__ f4l,
    const ushort_t* __restrict__ fgh, const ushort_t* __restrict__ fgl,
    const int* __restrict__ near1, const int* __restrict__ near2,
    const ushort_t* __restrict__ Bhi, const ushort_t* __restrict__ Blo,
    const float* __restrict__ bias, int K,
    float* __restrict__ outF, ushort_t* __restrict__ outHi,
    ushort_t* __restrict__ outLo, int Nn)
{
  __shared__ ushort_t As_h[128 * LDT];
  __shared__ ushort_t As_l[128 * LDT];
  __shared__ ushort_t Bs_h[128 * LDT];
  __shared__ ushort_t Bs_l[128 * LDT];

  const int tid  = threadIdx.x;
  const int lane = tid & 63;
  const int wv   = tid >> 6;
  const int wr   = wv >> 1, wc = wv & 1;
  const int quad = lane >> 4, ml = lane & 15;
  const int m0 = blockIdx.y * 128, n0 = blockIdx.x * 128;

  const int r  = tid >> 1;         // staging row 0..127
  const int hh = (tid & 1) * 16;   // 16-elem half of BK=32

  int fb = 0, r1 = 0, r2 = 0;
  if (FUSE) {
    const int m = m0 + r;
    fb = m >> 12;                  // / 4096
    r1 = near1[m];
    r2 = near2[m];
  }

  uint4 a0h, a1h, a0l, a1l, b0h, b1h, b0l, b1l;
  auto load_slice = [&](int k0) {
    const int k = k0 + hh;
    {
      const ushort_t *sh, *sl; size_t off;
      if (FUSE) {
        const int m = m0 + r;
        if (k < 128)       { sh = f0h; sl = f0l; off = (size_t)m * 128 + k; }
        else if (k < 256)  { sh = f1h; sl = f1l; off = (size_t)m * 128 + (k - 128); }
        else if (k < 512)  { sh = f2h; sl = f2l; off = ((size_t)fb * 1024 + r1) * 256 + (k - 256); }
        else if (k < 768)  { sh = f3h; sl = f3l; off = ((size_t)fb * 1024 + r1) * 256 + (k - 512); }
        else if (k < 1280) { sh = f4h; sl = f4l; off = ((size_t)fb * 256 + r2) * 512 + (k - 768); }
        else               { sh = fgh; sl = fgl; off = (size_t)fb * 512 + (k - 1280); }
      } else {
        sh = Ahi; sl = Alo; off = (size_t)(m0 + r) * K + k;
      }
      a0h = *(const uint4*)(sh + off); a1h = *(const uint4*)(sh + off + 8);
      a0l = *(const uint4*)(sl + off); a1l = *(const uint4*)(sl + off + 8);
    }
    {
      const size_t off = (size_t)(n0 + r) * K + k;
      b0h = *(const uint4*)(Bhi + off); b1h = *(const uint4*)(Bhi + off + 8);
      b0l = *(const uint4*)(Blo + off); b1l = *(const uint4*)(Blo + off + 8);
    }
  };

  f32x4 acc[4][4];
#pragma unroll
  for (int i = 0; i < 4; ++i)
#pragma unroll
    for (int j = 0; j < 4; ++j) acc[i][j] = f32x4{0.f, 0.f, 0.f, 0.f};

  load_slice(0);
  for (int k0 = 0; k0 < K; k0 += 32) {
    __syncthreads();   // previous iteration's fragment reads complete
    *(uint4*)&As_h[r * LDT + hh]     = a0h;
    *(uint4*)&As_h[r * LDT + hh + 8] = a1h;
    *(uint4*)&As_l[r * LDT + hh]     = a0l;
    *(uint4*)&As_l[r * LDT + hh + 8] = a1l;
    *(uint4*)&Bs_h[r * LDT + hh]     = b0h;
    *(uint4*)&Bs_h[r * LDT + hh + 8] = b1h;
    *(uint4*)&Bs_l[r * LDT + hh]     = b0l;
    *(uint4*)&Bs_l[r * LDT + hh + 8] = b1l;
    __syncthreads();
    if (k0 + 32 < K) load_slice(k0 + 32);   // prefetch overlaps MFMAs below

    bf16x8 ah[4], al[4], bh[4], bl[4];
#pragma unroll
    for (int i = 0; i < 4; ++i) {
      const int row = wr * 64 + i * 16 + ml;
      ah[i] = *(const bf16x8*)&As_h[row * LDT + quad * 8];
      al[i] = *(const bf16x8*)&As_l[row * LDT + quad * 8];
    }
#pragma unroll
    for (int j = 0; j < 4; ++j) {
      const int row = wc * 64 + j * 16 + ml;
      bh[j] = *(const bf16x8*)&Bs_h[row * LDT + quad * 8];
      bl[j] = *(const bf16x8*)&Bs_l[row * LDT + quad * 8];
    }
#pragma unroll
    for (int i = 0; i < 4; ++i)
#pragma unroll
      for (int j = 0; j < 4; ++j) {
        acc[i][j] = __builtin_amdgcn_mfma_f32_16x16x32_bf16(al[i], bh[j], acc[i][j], 0, 0, 0);
        acc[i][j] = __builtin_amdgcn_mfma_f32_16x16x32_bf16(ah[i], bl[j], acc[i][j], 0, 0, 0);
        acc[i][j] = __builtin_amdgcn_mfma_f32_16x16x32_bf16(ah[i], bh[j], acc[i][j], 0, 0, 0);
      }
  }

  // epilogue: C/D mapping col=lane&15, row=quad*4+reg (m89)
#pragma unroll
  for (int i = 0; i < 4; ++i)
#pragma unroll
    for (int j = 0; j < 4; ++j) {
      const int n = n0 + wc * 64 + j * 16 + ml;
      const float bv = bias[n];
#pragma unroll
      for (int reg = 0; reg < 4; ++reg) {
        const int m = m0 + wr * 64 + i * 16 + quad * 4 + reg;
        float r = acc[i][j][reg] + bv;
        if (RELU) r = fmaxf(r, 0.0f);
        if (SPLITOUT) {
          const ushort_t h = f2bf_rne(r);
          outHi[(size_t)m * Nn + n] = h;
          outLo[(size_t)m * Nn + n] = f2bf_rne(r - bf2f(h));
        } else {
          outF[(size_t)m * Nn + n] = r;
        }
      }
    }
}

// --------------------------------------------------- head: wave per row ----
__launch_bounds__(256)
__global__ void head_wave_kernel(const float* __restrict__ h,   // (16384, 512)
                                 const float* __restrict__ cw,  // (13, 512)
                                 const float* __restrict__ cb,  // (13,)
                                 float* __restrict__ out) {     // (16384, 13)
  __shared__ float ws[13 * 512];
  __shared__ float cbs[13];
  const int lane = threadIdx.x & 63;
  const int wid  = threadIdx.x >> 6;
  for (int i = threadIdx.x; i < 13 * 512; i += 256) ws[i] = cw[i];
  if (threadIdx.x < 13) cbs[threadIdx.x] = cb[threadIdx.x];
  __syncthreads();
  const int row = blockIdx.x * 4 + wid;
  const float4* hr = (const float4*)(h + (size_t)row * 512);
  const float4 a0 = hr[lane * 2], a1 = hr[lane * 2 + 1];
#pragma unroll
  for (int o = 0; o < 13; ++o) {
    const float4* wr = (const float4*)(ws + o * 512);
    const float4 w0 = wr[lane * 2], w1 = wr[lane * 2 + 1];
    float p = a0.x * w0.x + a0.y * w0.y + a0.z * w0.z + a0.w * w0.w
            + a1.x * w1.x + a1.y * w1.y + a1.z * w1.z + a1.w * w1.w;
#pragma unroll
    for (int j = 1; j < 64; j <<= 1) p += __shfl_xor(p, j);
    if (lane == 0) out[(size_t)row * 13 + o] = p + cbs[o];
  }
}

} // namespace

extern "C" void kernel_launch(void* const* d_in, const int* in_sizes, int n_in,
                              void* d_out, int out_size, void* d_ws, size_t ws_size,
                              hipStream_t stream)
{
  const float* vertices = (const float*)d_in[0];
  const int*   sidx1    = (const int*)  d_in[1];
  const int*   sidx2    = (const int*)  d_in[2];
  const float* dir0     = (const float*)d_in[3];
  const float* w1 = (const float*)d_in[4];
  const float* b1 = (const float*)d_in[5];
  const float* d1 = (const float*)d_in[6];
  const float* w2 = (const float*)d_in[7];
  const float* b2 = (const float*)d_in[8];
  const float* d2 = (const float*)d_in[9];
  const float* w3 = (const float*)d_in[10];
  const float* b3 = (const float*)d_in[11];
  const float* d3 = (const float*)d_in[12];
  const float* w4 = (const float*)d_in[13];
  const float* b4 = (const float*)d_in[14];
  const float* d4 = (const float*)d_in[15];
  const float* cw1 = (const float*)d_in[16];
  const float* cb1 = (const float*)d_in[17];
  const float* cw2 = (const float*)d_in[18];
  const float* cb2 = (const float*)d_in[19];
  const float* cw3 = (const float*)d_in[20];
  const float* cb3 = (const float*)d_in[21];
  (void)in_sizes; (void)n_in; (void)out_size; (void)ws_size;

  char* ws = (char*)d_ws;
  size_t off = 0;
  auto alloc = [&](size_t bytes) -> void* {
    void* p = ws + off;
    off += (bytes + 255) & ~(size_t)255;
    return p;
  };

  int*   nb1   = (int*)  alloc((size_t)B_ * N0 * 32 * 4);
  int*   nb2   = (int*)  alloc((size_t)B_ * N1 * 32 * 4);
  int*   nb3   = (int*)  alloc((size_t)B_ * N2 * 32 * 4);
  float* vp1   = (float*)alloc((size_t)B_ * N1 * 3 * 4);
  float* vp2   = (float*)alloc((size_t)B_ * N2 * 3 * 4);
  int*   near1 = (int*)  alloc((size_t)B_ * N0 * 4);
  int*   near2 = (int*)  alloc((size_t)B_ * N0 * 4);
  float* h2    = (float*)alloc((size_t)B_ * N0 * 512 * 4);   // 32 MB
  float* fbuf  = (float*)alloc((size_t)B_ * N0 * 256 * 4);   // 16 MB

  const size_t nF0 = (size_t)B_ * N0 * 128;   // fm0 / fm1
  const size_t nP1 = (size_t)B_ * N1 * 128;   // fmp1
  const size_t nF2 = (size_t)B_ * N1 * 256;   // fm2 / fm3
  const size_t nP2 = (size_t)B_ * N2 * 256;   // fmp2
  const size_t nF4 = (size_t)B_ * N2 * 512;
  const size_t nFg = (size_t)B_ * 512;
  const size_t nW1 = (size_t)512 * 1792;
  const size_t nW2 = (size_t)512 * 512;
  const size_t nH1 = (size_t)B_ * N0 * 512;
  ushort_t* f0h = (ushort_t*)alloc(nF0 * 2); ushort_t* f0l = (ushort_t*)alloc(nF0 * 2);
  ushort_t* f1h = (ushort_t*)alloc(nF0 * 2); ushort_t* f1l = (ushort_t*)alloc(nF0 * 2);
  ushort_t* p1h = (ushort_t*)alloc(nP1 * 2); ushort_t* p1l = (ushort_t*)alloc(nP1 * 2);
  ushort_t* f2h = (ushort_t*)alloc(nF2 * 2); ushort_t* f2l = (ushort_t*)alloc(nF2 * 2);
  ushort_t* f3h = (ushort_t*)alloc(nF2 * 2); ushort_t* f3l = (ushort_t*)alloc(nF2 * 2);
  ushort_t* p2h = (ushort_t*)alloc(nP2 * 2); ushort_t* p2l = (ushort_t*)alloc(nP2 * 2);
  ushort_t* f4h = (ushort_t*)alloc(nF4 * 2); ushort_t* f4l = (ushort_t*)alloc(nF4 * 2);
  ushort_t* fgh = (ushort_t*)alloc(nFg * 2); ushort_t* fgl = (ushort_t*)alloc(nFg * 2);
  ushort_t* w1h = (ushort_t*)alloc(nW1 * 2); ushort_t* w1l = (ushort_t*)alloc(nW1 * 2);
  ushort_t* w2h = (ushort_t*)alloc(nW2 * 2); ushort_t* w2l = (ushort_t*)alloc(nW2 * 2);
  ushort_t* h1h = (ushort_t*)alloc(nH1 * 2); ushort_t* h1l = (ushort_t*)alloc(nH1 * 2);
  ushort_t* w1th = (ushort_t*)alloc((size_t)256 * 128 * 2);
  ushort_t* w1tl = (ushort_t*)alloc((size_t)256 * 128 * 2);
  ushort_t* w2th = (ushort_t*)alloc((size_t)512 * 128 * 2);
  ushort_t* w2tl = (ushort_t*)alloc((size_t)512 * 128 * 2);
  ushort_t* w3th = (ushort_t*)alloc((size_t)512 * 256 * 2);
  ushort_t* w3tl = (ushort_t*)alloc((size_t)512 * 256 * 2);
  ushort_t* w4th = (ushort_t*)alloc((size_t)1024 * 256 * 2);
  ushort_t* w4tl = (ushort_t*)alloc((size_t)1024 * 256 * 2);

  const dim3 blk256(256), blk512(512);
  auto mgemm = [&](const ushort_t* Ah, const ushort_t* Al,
                   const ushort_t* Bh, const ushort_t* Bl, const float* bias,
                   int M, int Nn, int K, float* outF) {
    const dim3 grid(Nn / 128, M / 128);
    mfma_gemm_kernel<false, false, false><<<grid, blk256, 0, stream>>>(
        Ah, Al, nullptr, nullptr, nullptr, nullptr, nullptr, nullptr, nullptr,
        nullptr, nullptr, nullptr, nullptr, nullptr, nullptr, nullptr,
        Bh, Bl, bias, K, outF, nullptr, nullptr, Nn);
  };

  // ---- prep: weights + vp1/vp2 in one dispatch ----
  prep_kernel<<<dim3(6588), blk256, 0, stream>>>(
      w1, w2, w3, w4, cw1, cw2, vertices, sidx1, sidx2,
      w1th, w1tl, w2th, w2tl, w3th, w3tl, w4th, w4tl,
      w1h, w1l, w2h, w2l, vp1, vp2);

  // ---- all three KNN levels, one dispatch ----
  knn_mega_kernel<<<dim3(2688), blk512, 0, stream>>>(
      vertices, vp1, vp2, nb1, nb2, nb3);

  // ---- level 0 (4096 verts) ----
  conv_surface_kernel<<<dim3(B_ * N0), dim3(128), 0, stream>>>(
      vertices, nb1, dir0, N0, 128, f0h, f0l);
  mgemm(f0h, f0l, w1th, w1tl, b1, B_ * N0, 256, 128, fbuf);
  conv_combine_kernel<<<dim3(B_ * N0), dim3(128), 0, stream>>>(
      fbuf, nb1, d1, vertices, N0, 128, 1, f1h, f1l);

  // ---- pool 1 -> 1024 (top-4 = first 4 of nb1 rows at sidx1) ----
  pool_kernel<<<dim3((B_ * N1 * 128 + 255) / 256), blk256, 0, stream>>>(
      f1h, f1l, nb1, sidx1, N1, N0, 128, p1h, p1l);

  // ---- level 1 (1024 verts) ----
  mgemm(p1h, p1l, w2th, w2tl, b2, B_ * N1, 512, 128, fbuf);
  conv_combine_kernel<<<dim3(B_ * N1), dim3(256), 0, stream>>>(
      fbuf, nb2, d2, vp1, N1, 256, 1, f2h, f2l);
  mgemm(f2h, f2l, w3th, w3tl, b3, B_ * N1, 512, 256, fbuf);
  conv_combine_kernel<<<dim3(B_ * N1), dim3(256), 0, stream>>>(
      fbuf, nb2, d3, vp1, N1, 256, 1, f3h, f3l);

  // ---- pool 2 -> 256 ----
  pool_kernel<<<dim3((B_ * N2 * 256 + 255) / 256), blk256, 0, stream>>>(
      f3h, f3l, nb2, sidx2, N2, N1, 256, p2h, p2l);

  // ---- level 2 (256 verts) ----
  mgemm(p2h, p2l, w4th, w4tl, b4, B_ * N2, 1024, 256, fbuf);
  conv_combine_kernel<<<dim3(B_ * N2), dim3(512), 0, stream>>>(
      fbuf, nb3, d4, vp2, N2, 512, 0, f4h, f4l);     // no relu on fm_4
  global_max_kernel<<<dim3(B_ * 8), blk256, 0, stream>>>(f4h, f4l, fgh, fgl);

  // ---- upsample indices: both levels in one dispatch ----
  nearest_dual_kernel<<<dim3((B_ * N0) / 4, 2), blk256, 0, stream>>>(
      vertices, vp1, vp2, near1, near2);

  // ---- head MLP ----
  mfma_gemm_kernel<true, true, true><<<dim3(512 / 128, (B_ * N0) / 128), blk256, 0, stream>>>(
      nullptr, nullptr,
      f0h, f0l, f1h, f1l, f2h, f2l, f3h, f3l, f4h, f4l, fgh, fgl,
      near1, near2, w1h, w1l, cb1, 1792, nullptr, h1h, h1l, 512);
  mfma_gemm_kernel<false, false, true><<<dim3(512 / 128, (B_ * N0) / 128), blk256, 0, stream>>>(
      h1h, h1l,
      nullptr, nullptr, nullptr, nullptr, nullptr, nullptr, nullptr, nullptr,
      nullptr, nullptr, nullptr, nullptr,
      nullptr, nullptr, w2h, w2l, cb2, 512, h2, nullptr, nullptr, 512);
  head_wave_kernel<<<dim3((B_ * N0) / 4), blk256, 0, stream>>>(
      h2, cw3, cb3, (float*)d_out);
}

// Round 15
// 580.686 us; speedup vs baseline: 1.0020x; 1.0020x over previous
//
#include <hip/hip_runtime.h>
#include <cstdint>
#include <cstddef>

namespace {

typedef unsigned short ushort_t;
typedef __bf16 bf16x8 __attribute__((ext_vector_type(8)));
typedef float  f32x4  __attribute__((ext_vector_type(4)));

constexpr int B_ = 4;
constexpr int N0 = 4096;   // vertices per batch
constexpr int N1 = 1024;   // after pool1
constexpr int N2 = 256;    // after pool2

// ----------------------------------------------------- bf16 split utils ----
__device__ __forceinline__ ushort_t f2bf_rne(float x) {
  uint32_t b = __float_as_uint(x);
  b += 0x7FFFu + ((b >> 16) & 1u);
  return (ushort_t)(b >> 16);
}
__device__ __forceinline__ float bf2f(ushort_t h) {
  return __uint_as_float(((uint32_t)h) << 16);
}
__device__ __forceinline__ void split_store(float x, ushort_t* hi, ushort_t* lo,
                                            size_t i) {
  const ushort_t h = f2bf_rne(x);
  hi[i] = h;
  lo[i] = f2bf_rne(x - bf2f(h));
}

// ------------------- fused prep: weight split/transpose + vp1/vp2 gather ---
__global__ void prep_kernel(
    const float* __restrict__ w1, const float* __restrict__ w2,
    const float* __restrict__ w3, const float* __restrict__ w4,
    const float* __restrict__ cw1, const float* __restrict__ cw2,
    const float* __restrict__ vertices,
    const int* __restrict__ sidx1, const int* __restrict__ sidx2,
    ushort_t* __restrict__ w1th, ushort_t* __restrict__ w1tl,
    ushort_t* __restrict__ w2th, ushort_t* __restrict__ w2tl,
    ushort_t* __restrict__ w3th, ushort_t* __restrict__ w3tl,
    ushort_t* __restrict__ w4th, ushort_t* __restrict__ w4tl,
    ushort_t* __restrict__ w1h, ushort_t* __restrict__ w1l,
    ushort_t* __restrict__ w2h, ushort_t* __restrict__ w2l,
    float* __restrict__ vp1, float* __restrict__ vp2)
{
  const int i = blockIdx.x * blockDim.x + threadIdx.x;
  if (i < 32768) {                       // w1: K=128, N=256
    const int j = i, k = j % 128, n = j / 128;
    split_store(w1[(size_t)k * 256 + n], w1th, w1tl, (size_t)n * 128 + k);
  } else if (i < 98304) {                // w2: K=128, N=512
    const int j = i - 32768, k = j % 128, n = j / 128;
    split_store(w2[(size_t)k * 512 + n], w2th, w2tl, (size_t)n * 128 + k);
  } else if (i < 229376) {               // w3: K=256, N=512
    const int j = i - 98304, k = j % 256, n = j / 256;
    split_store(w3[(size_t)k * 512 + n], w3th, w3tl, (size_t)n * 256 + k);
  } else if (i < 491520) {               // w4: K=256, N=1024
    const int j = i - 229376, k = j % 256, n = j / 256;
    split_store(w4[(size_t)k * 1024 + n], w4th, w4tl, (size_t)n * 256 + k);
  } else if (i < 1409024) {              // cw1: already (N,K)
    const int j = i - 491520;
    split_store(cw1[j], w1h, w1l, j);
  } else if (i < 1671168) {              // cw2
    const int j = i - 1409024;
    split_store(cw2[j], w2h, w2l, j);
  } else if (i < 1683456) {              // vp1 = vertices[:, sidx1, :]
    const int j = i - 1671168;
    const int c = j % 3, q = (j / 3) % N1, b = j / (3 * N1);
    vp1[j] = vertices[((size_t)b * N0 + sidx1[q]) * 3 + c];
  } else if (i < 1686528) {              // vp2 = vertices[:, sidx1[sidx2], :]
    const int j = i - 1683456;
    const int c = j % 3, q = (j / 3) % N2, b = j / (3 * N2);
    vp2[j] = vertices[((size_t)b * N0 + sidx1[sidx2[q]]) * 3 + c];
  }
}

// ------------------------------------------------- wave-cooperative KNN ----
__device__ __forceinline__ void bitonic_sort64(float& sd, int& si, int lane) {
#pragma unroll
  for (int kk = 2; kk <= 64; kk <<= 1) {
#pragma unroll
    for (int j = kk >> 1; j > 0; j >>= 1) {
      const float od = __shfl_xor(sd, j);
      const int   oi = __shfl_xor(si, j);
      const bool less    = (sd < od) || (sd == od && si < oi);
      const bool wantMin = ((lane & j) == 0) == ((lane & kk) == 0);
      if (wantMin != less) { sd = od; si = oi; }
    }
  }
}

__device__ __forceinline__ void knn_flush(float& ld, int& li, float& tau,
                                          int cnt, const float* bufd,
                                          const int* bufi, int lane, int Km1) {
  float sd = (lane < cnt) ? bufd[lane] : INFINITY;
  int   si = (lane < cnt) ? bufi[lane] : 0x7fffffff;
  bitonic_sort64(sd, si, lane);
  const float rd = __shfl(sd, 63 - lane);
  const int   ri = __shfl(si, 63 - lane);
  const bool keep = (ld < rd) || (ld == rd && li < ri);
  float md = keep ? ld : rd;
  int   mi = keep ? li : ri;
#pragma unroll
  for (int j = 32; j > 0; j >>= 1) {
    const float od = __shfl_xor(md, j);
    const int   oi = __shfl_xor(mi, j);
    const bool less    = (md < od) || (md == od && mi < oi);
    const bool wantMin = ((lane & j) == 0);
    if (wantMin != less) { md = od; mi = oi; }
  }
  ld = md; li = mi;
  tau = __shfl(ld, Km1);
}

// MEGA kernel: 3 KNN levels + inline fm0 (conv_surface) + both nearest
// argmins, one dispatch. Flat grid (6784 blocks, 512 thr):
//   [0,2048)      L0 KNN + fm0 epilogue (top-32 is in registers)
//   [2048,2560)   L1 KNN
//   [2560,2688)   L2 KNN
//   [2688,4736)   nearest vs vp1 (8 queries/block)
//   [4736,6784)   nearest vs vp2
__launch_bounds__(512)
__global__ void mega_kernel(const float* __restrict__ verts,
                            const float* __restrict__ vp1,
                            const float* __restrict__ vp2,
                            const float* __restrict__ dir,   // (3,128)
                            int* __restrict__ nb1,
                            int* __restrict__ nb2,
                            int* __restrict__ nb3,
                            ushort_t* __restrict__ f0h,
                            ushort_t* __restrict__ f0l,
                            int* __restrict__ near1,
                            int* __restrict__ near2)
{
  constexpr int K = 32, TILE = 2048;
  __shared__ float4 sp[TILE];
  __shared__ float sbd[8][64];
  __shared__ int   sbi[8][64];

  int bx = blockIdx.x;
  const int lane = threadIdx.x & 63;
  const int wid  = threadIdx.x >> 6;

  if (bx >= 2688) {
    // ---------------- nearest segment ----------------
    const int seg = bx - 2688;
    const int lvl = seg >> 11;             // 2048 blocks per level
    const int sb  = seg & 2047;
    const int C   = lvl ? N2 : N1;
    const float* cpts = lvl ? vp2 : vp1;
    int* out = lvl ? near2 : near1;
    const int q = sb * 8 + wid;            // over B_*N0 (batch-aligned: 4096%8==0)
    const int b = q >> 12;
    const float qx = verts[(size_t)q * 3 + 0];
    const float qy = verts[(size_t)q * 3 + 1];
    const float qz = verts[(size_t)q * 3 + 2];
    const float q2   = qx * qx + qy * qy + qz * qz;
    const float m2qx = -2.0f * qx, m2qy = -2.0f * qy, m2qz = -2.0f * qz;
    const float* pb = cpts + (size_t)b * C * 3;
    for (int i = threadIdx.x; i < C; i += 512) {
      const float x = pb[i * 3 + 0];
      const float y = pb[i * 3 + 1];
      const float z = pb[i * 3 + 2];
      sp[i] = make_float4(x, y, z, x * x + y * y + z * z);
    }
    __syncthreads();
    float best = INFINITY; int bi = 0x7fffffff;
    for (int base = 0; base < C; base += 64) {
      const float4 p = sp[base + lane];
      const float d = fmaf(m2qx, p.x, fmaf(m2qy, p.y, fmaf(m2qz, p.z, p.w + q2)));
      if (d < best) { best = d; bi = base + lane; }   // idx ascends: first min kept
    }
#pragma unroll
    for (int j = 1; j < 64; j <<= 1) {
      const float od = __shfl_xor(best, j);
      const int   oi = __shfl_xor(bi, j);
      if (od < best || (od == best && oi < bi)) { best = od; bi = oi; }
    }
    if (lane == 0) out[q] = bi;
    return;
  }

  // ---------------- KNN segment ----------------
  const float* pts; int Q, C; int* out; bool isL0 = false;
  if (bx < 2048)      { pts = verts; Q = N0; C = N0; out = nb1; isL0 = true; }
  else if (bx < 2560) { pts = vp1;   Q = N1; C = N1; out = nb2; bx -= 2048; }
  else                { pts = vp2;   Q = N2; C = N2; out = nb3; bx -= 2560; }
  const int bpb = Q / 8;
  const int b  = bx / bpb;
  const int q    = (bx % bpb) * 8 + wid;
  const int self = q;
  const float* pb = pts + (size_t)b * C * 3;
  const float qx = pb[self * 3 + 0];
  const float qy = pb[self * 3 + 1];
  const float qz = pb[self * 3 + 2];
  const float q2   = qx * qx + qy * qy + qz * qz;
  const float m2qx = -2.0f * qx, m2qy = -2.0f * qy, m2qz = -2.0f * qz;

  float ld = INFINITY; int li = 0x7fffffff;
  float tau = INFINITY;
  int cnt = 0;
  float* bufd = sbd[wid];
  int*   bufi = sbi[wid];

  auto append = [&](unsigned long long m, bool cand, float d, int ci) {
    const int c = __popcll(m);
    if (cnt + c > 64) {
      knn_flush(ld, li, tau, cnt, bufd, bufi, lane, K - 1);
      cnt = 0;
    }
    const int prefix = __popcll(m & ((1ull << lane) - 1ull));
    if (cand) { bufd[cnt + prefix] = d; bufi[cnt + prefix] = ci; }
    cnt += c;
  };

  for (int t0 = 0; t0 < C; t0 += TILE) {
    const int nt = (C - t0 < TILE) ? (C - t0) : TILE;
    __syncthreads();
    for (int i = threadIdx.x; i < nt; i += 512) {
      const float x = pb[(t0 + i) * 3 + 0];
      const float y = pb[(t0 + i) * 3 + 1];
      const float z = pb[(t0 + i) * 3 + 2];
      sp[i] = make_float4(x, y, z, x * x + y * y + z * z);
    }
    __syncthreads();
    int base = 0;
    if (t0 == 0) {
      const float4 p = sp[lane];
      const float d = fmaf(m2qx, p.x, fmaf(m2qy, p.y, fmaf(m2qz, p.z, p.w + q2)));
      const bool valid = (lane != self);
      float sd = valid ? d : INFINITY;
      int   si = valid ? lane : 0x7fffffff;
      bitonic_sort64(sd, si, lane);
      ld = sd; li = si;
      tau = __shfl(ld, K - 1);
      base = 64;
    }
    for (; base + 128 <= nt; base += 128) {
      const int ci0 = t0 + base + lane;
      const int ci1 = ci0 + 64;
      const float4 p0 = sp[base + lane];
      const float4 p1 = sp[base + 64 + lane];
      const float d0 = fmaf(m2qx, p0.x, fmaf(m2qy, p0.y, fmaf(m2qz, p0.z, p0.w + q2)));
      const float d1 = fmaf(m2qx, p1.x, fmaf(m2qy, p1.y, fmaf(m2qz, p1.z, p1.w + q2)));
      const bool c0 = (ci0 != self) && (d0 < tau);
      const bool c1 = (ci1 != self) && (d1 < tau);
      const unsigned long long m0 = __ballot(c0);
      const unsigned long long m1 = __ballot(c1);
      if (m0) append(m0, c0, d0, ci0);
      if (m1) append(m1, c1, d1, ci1);
    }
    if (base < nt) {
      const int ci = t0 + base + lane;
      const float4 p = sp[base + lane];
      const float d = fmaf(m2qx, p.x, fmaf(m2qy, p.y, fmaf(m2qz, p.z, p.w + q2)));
      const bool c = (ci != self) && (d < tau);
      const unsigned long long m = __ballot(c);
      if (m) append(m, c, d, ci);
    }
  }
  if (cnt > 0) knn_flush(ld, li, tau, cnt, bufd, bufi, lane, K - 1);
  if (lane < K) out[((size_t)b * Q + q) * K + lane] = li;

  if (isL0) {
    // ---- inline conv_surface: fm0 from the in-register top-32 ----
    float ux = 0.f, uy = 0.f, uz = 0.f;
    if (lane < 32) {
      const float dx = pb[li * 3 + 0] - qx;
      const float dy = pb[li * 3 + 1] - qy;
      const float dz = pb[li * 3 + 2] - qz;
      const float rn = 1.0f / fmaxf(sqrtf(dx * dx + dy * dy + dz * dz), 1e-12f);
      ux = dx * rn; uy = dy * rn; uz = dz * rn;
    }
    const int o1 = lane, o2 = lane + 64;
    float d0a = dir[o1], d1a = dir[128 + o1], d2a = dir[256 + o1];
    const float rna = 1.0f / fmaxf(sqrtf(d0a*d0a + d1a*d1a + d2a*d2a), 1e-12f);
    d0a *= rna; d1a *= rna; d2a *= rna;
    float d0b = dir[o2], d1b = dir[128 + o2], d2b = dir[256 + o2];
    const float rnb = 1.0f / fmaxf(sqrtf(d0b*d0b + d1b*d1b + d2b*d2b), 1e-12f);
    d0b *= rnb; d1b *= rnb; d2b *= rnb;
    float ma = -INFINITY, mb = -INFINITY;
#pragma unroll 8
    for (int n = 0; n < 32; ++n) {
      const float nx = __shfl(ux, n);
      const float ny = __shfl(uy, n);
      const float nz = __shfl(uz, n);
      const float ta = fmaxf(0.0f, fmaf(d2a, nz, fmaf(d1a, ny, d0a * nx)));
      const float tb = fmaxf(0.0f, fmaf(d2b, nz, fmaf(d1b, ny, d0b * nx)));
      ma = fmaxf(ma, ta); mb = fmaxf(mb, tb);
    }
    const size_t baseo = ((size_t)b * N0 + q) * 128;
    split_store(fmaxf(0.0f, ma), f0h, f0l, baseo + o1);
    split_store(fmaxf(0.0f, mb), f0h, f0l, baseo + o2);
  }
}

// -------------------------------------------------------- conv_combine -----
__global__ void conv_combine_kernel(const float* __restrict__ f,    // (B,V,2C)
                                    const int*   __restrict__ nb,
                                    const float* __restrict__ dir,
                                    const float* __restrict__ verts,
                                    int V, int C, int relu,
                                    ushort_t* __restrict__ outH,
                                    ushort_t* __restrict__ outL) {
  __shared__ float ux[32], uy[32], uz[32];
  __shared__ int snb[32];
  const int bv = blockIdx.x;
  const int b = bv / V;
  const int v = bv - b * V;
  const float* vb = verts + (size_t)b * V * 3;
  if (threadIdx.x < 32) {
    const float cx = vb[v * 3 + 0], cy = vb[v * 3 + 1], cz = vb[v * 3 + 2];
    const int nidx = nb[(size_t)bv * 32 + threadIdx.x];
    snb[threadIdx.x] = nidx;
    const float dx = vb[nidx * 3 + 0] - cx;
    const float dy = vb[nidx * 3 + 1] - cy;
    const float dz = vb[nidx * 3 + 2] - cz;
    const float rn = 1.0f / fmaxf(sqrtf(dx * dx + dy * dy + dz * dz), 1e-12f);
    ux[threadIdx.x] = dx * rn; uy[threadIdx.x] = dy * rn; uz[threadIdx.x] = dz * rn;
  }
  __syncthreads();
  const int o = threadIdx.x;
  float d0 = dir[o], d1 = dir[C + o], d2 = dir[2 * C + o];
  const float rn = 1.0f / fmaxf(sqrtf(d0 * d0 + d1 * d1 + d2 * d2), 1e-12f);
  d0 *= rn; d1 *= rn; d2 *= rn;
  const float* fb = f + (size_t)b * V * 2 * C;
  float m = -INFINITY;
#pragma unroll 8
  for (int n = 0; n < 32; ++n) {
    const float t = fmaxf(0.0f, fmaf(d2, uz[n], fmaf(d1, uy[n], d0 * ux[n])));
    const float s = fb[(size_t)snb[n] * 2 * C + C + o];
    m = fmaxf(m, t * s);
  }
  float r = fb[(size_t)v * 2 * C + o] + m;
  if (relu) r = fmaxf(r, 0.0f);
  split_store(r, outH, outL, (size_t)bv * C + o);
}

// ---------------------------------------------------------------- pool -----
__global__ void pool_kernel(const ushort_t* __restrict__ fmH,
                            const ushort_t* __restrict__ fmL,
                            const int*   __restrict__ nb,   // (B, Vsrc, 32)
                            const int*   __restrict__ sidx, // (Q,)
                            int Q, int Vsrc, int C,
                            ushort_t* __restrict__ outH,
                            ushort_t* __restrict__ outL) {
  const int i = blockIdx.x * blockDim.x + threadIdx.x;
  if (i >= B_ * Q * C) return;
  const int c = i % C;
  const int q = (i / C) % Q;
  const int b = i / (C * Q);
  const int* nn = nb + ((size_t)b * Vsrc + sidx[q]) * 32;
  const size_t fb = (size_t)b * Vsrc * C;
  float m = -INFINITY;
#pragma unroll
  for (int t = 0; t < 4; ++t) {
    const size_t idx = fb + (size_t)nn[t] * C + c;
    m = fmaxf(m, bf2f(fmH[idx]) + bf2f(fmL[idx]));
  }
  split_store(m, outH, outL, (size_t)i);
}

// grid = B_*8 blocks of 256 thr: 64 channels x 4 v-slices per block
__global__ void global_max_kernel(const ushort_t* __restrict__ fmH,
                                  const ushort_t* __restrict__ fmL,
                                  ushort_t* __restrict__ outH,
                                  ushort_t* __restrict__ outL) {
  __shared__ float red[4][64];
  const int t = threadIdx.x;
  const int cl = t & 63, slice = t >> 6;
  const int c = (blockIdx.x & 7) * 64 + cl;
  const int b = blockIdx.x >> 3;
  const size_t base = (size_t)b * 256 * 512 + c;
  float m = -INFINITY;
  for (int v = slice; v < 256; v += 4) {
    const size_t idx = base + (size_t)v * 512;
    m = fmaxf(m, bf2f(fmH[idx]) + bf2f(fmL[idx]));
  }
  red[slice][cl] = m;
  __syncthreads();
  if (slice == 0) {
    m = fmaxf(fmaxf(red[0][cl], red[1][cl]), fmaxf(red[2][cl], red[3][cl]));
    split_store(m, outH, outL, (size_t)b * 512 + c);
  }
}

// ------------------------------------------- split-bf16 MFMA GEMM ----------
constexpr int LDT = 36;  // LDS row stride in ushorts (32 + 4 pad)

template<bool FUSE, bool SPLITOUT, bool RELU>
__launch_bounds__(256)
__global__ void mfma_gemm_kernel(
    const ushort_t* __restrict__ Ahi, const ushort_t* __restrict__ Alo,
    const ushort_t* __restrict__ f0h, const ushort_t* __restrict__ f0l,
    const ushort_t* __restrict__ f1h, const ushort_t* __restrict__ f1l,
    const ushort_t* __restrict__ f2h, const ushort_t* __restrict__ f2l,
    const ushort_t* __restrict__ f3h, const ushort_t* __restrict__ f3l,
    const ushort_t* __restrict__ f4h, const ushort_t* __restrict__ f4l,
    const ushort_t* __restrict__ fgh, const ushort_t* __restrict__ fgl,
    const int* __restrict__ near1, const int* __restrict__ near2,
    const ushort_t* __restrict__ Bhi, const ushort_t* __restrict__ Blo,
    const float* __restrict__ bias, int K,
    float* __restrict__ outF, ushort_t* __restrict__ outHi,
    ushort_t* __restrict__ outLo, int Nn)
{
  __shared__ ushort_t As_h[128 * LDT];
  __shared__ ushort_t As_l[128 * LDT];
  __shared__ ushort_t Bs_h[128 * LDT];
  __shared__ ushort_t Bs_l[128 * LDT];

  const int tid  = threadIdx.x;
  const int lane = tid & 63;
  const int wv   = tid >> 6;
  const int wr   = wv >> 1, wc = wv & 1;
  const int quad = lane >> 4, ml = lane & 15;
  const int m0 = blockIdx.y * 128, n0 = blockIdx.x * 128;

  const int r  = tid >> 1;         // staging row 0..127
  const int hh = (tid & 1) * 16;   // 16-elem half of BK=32

  int fb = 0, r1 = 0, r2 = 0;
  if (FUSE) {
    const int m = m0 + r;
    fb = m >> 12;                  // / 4096
    r1 = near1[m];
    r2 = near2[m];
  }

  uint4 a0h, a1h, a0l, a1l, b0h, b1h, b0l, b1l;
  auto load_slice = [&](int k0) {
    const int k = k0 + hh;
    {
      const ushort_t *sh, *sl; size_t off;
      if (FUSE) {
        const int m = m0 + r;
        if (k < 128)       { sh = f0h; sl = f0l; off = (size_t)m * 128 + k; }
        else if (k < 256)  { sh = f1h; sl = f1l; off = (size_t)m * 128 + (k - 128); }
        else if (k < 512)  { sh = f2h; sl = f2l; off = ((size_t)fb * 1024 + r1) * 256 + (k - 256); }
        else if (k < 768)  { sh = f3h; sl = f3l; off = ((size_t)fb * 1024 + r1) * 256 + (k - 512); }
        else if (k < 1280) { sh = f4h; sl = f4l; off = ((size_t)fb * 256 + r2) * 512 + (k - 768); }
        else               { sh = fgh; sl = fgl; off = (size_t)fb * 512 + (k - 1280); }
      } else {
        sh = Ahi; sl = Alo; off = (size_t)(m0 + r) * K + k;
      }
      a0h = *(const uint4*)(sh + off); a1h = *(const uint4*)(sh + off + 8);
      a0l = *(const uint4*)(sl + off); a1l = *(const uint4*)(sl + off + 8);
    }
    {
      const size_t off = (size_t)(n0 + r) * K + k;
      b0h = *(const uint4*)(Bhi + off); b1h = *(const uint4*)(Bhi + off + 8);
      b0l = *(const uint4*)(Blo + off); b1l = *(const uint4*)(Blo + off + 8);
    }
  };

  f32x4 acc[4][4];
#pragma unroll
  for (int i = 0; i < 4; ++i)
#pragma unroll
    for (int j = 0; j < 4; ++j) acc[i][j] = f32x4{0.f, 0.f, 0.f, 0.f};

  load_slice(0);
  for (int k0 = 0; k0 < K; k0 += 32) {
    __syncthreads();
    *(uint4*)&As_h[r * LDT + hh]     = a0h;
    *(uint4*)&As_h[r * LDT + hh + 8] = a1h;
    *(uint4*)&As_l[r * LDT + hh]     = a0l;
    *(uint4*)&As_l[r * LDT + hh + 8] = a1l;
    *(uint4*)&Bs_h[r * LDT + hh]     = b0h;
    *(uint4*)&Bs_h[r * LDT + hh + 8] = b1h;
    *(uint4*)&Bs_l[r * LDT + hh]     = b0l;
    *(uint4*)&Bs_l[r * LDT + hh + 8] = b1l;
    __syncthreads();
    if (k0 + 32 < K) load_slice(k0 + 32);   // prefetch overlaps MFMAs below

    bf16x8 ah[4], al[4], bh[4], bl[4];
#pragma unroll
    for (int i = 0; i < 4; ++i) {
      const int row = wr * 64 + i * 16 + ml;
      ah[i] = *(const bf16x8*)&As_h[row * LDT + quad * 8];
      al[i] = *(const bf16x8*)&As_l[row * LDT + quad * 8];
    }
#pragma unroll
    for (int j = 0; j < 4; ++j) {
      const int row = wc * 64 + j * 16 + ml;
      bh[j] = *(const bf16x8*)&Bs_h[row * LDT + quad * 8];
      bl[j] = *(const bf16x8*)&Bs_l[row * LDT + quad * 8];
    }
#pragma unroll
    for (int i = 0; i < 4; ++i)
#pragma unroll
      for (int j = 0; j < 4; ++j) {
        acc[i][j] = __builtin_amdgcn_mfma_f32_16x16x32_bf16(al[i], bh[j], acc[i][j], 0, 0, 0);
        acc[i][j] = __builtin_amdgcn_mfma_f32_16x16x32_bf16(ah[i], bl[j], acc[i][j], 0, 0, 0);
        acc[i][j] = __builtin_amdgcn_mfma_f32_16x16x32_bf16(ah[i], bh[j], acc[i][j], 0, 0, 0);
      }
  }

  // epilogue: C/D mapping col=lane&15, row=quad*4+reg (m89)
#pragma unroll
  for (int i = 0; i < 4; ++i)
#pragma unroll
    for (int j = 0; j < 4; ++j) {
      const int n = n0 + wc * 64 + j * 16 + ml;
      const float bv = bias[n];
#pragma unroll
      for (int reg = 0; reg < 4; ++reg) {
        const int m = m0 + wr * 64 + i * 16 + quad * 4 + reg;
        float r = acc[i][j][reg] + bv;
        if (RELU) r = fmaxf(r, 0.0f);
        if (SPLITOUT) {
          const ushort_t h = f2bf_rne(r);
          outHi[(size_t)m * Nn + n] = h;
          outLo[(size_t)m * Nn + n] = f2bf_rne(r - bf2f(h));
        } else {
          outF[(size_t)m * Nn + n] = r;
        }
      }
    }
}

// --------------------------------------------------- head: wave per row ----
__launch_bounds__(256)
__global__ void head_wave_kernel(const float* __restrict__ h,   // (16384, 512)
                                 const float* __restrict__ cw,  // (13, 512)
                                 const float* __restrict__ cb,  // (13,)
                                 float* __restrict__ out) {     // (16384, 13)
  __shared__ float ws[13 * 512];
  __shared__ float cbs[13];
  const int lane = threadIdx.x & 63;
  const int wid  = threadIdx.x >> 6;
  for (int i = threadIdx.x; i < 13 * 512; i += 256) ws[i] = cw[i];
  if (threadIdx.x < 13) cbs[threadIdx.x] = cb[threadIdx.x];
  __syncthreads();
  const int row = blockIdx.x * 4 + wid;
  const float4* hr = (const float4*)(h + (size_t)row * 512);
  const float4 a0 = hr[lane * 2], a1 = hr[lane * 2 + 1];
#pragma unroll
  for (int o = 0; o < 13; ++o) {
    const float4* wr = (const float4*)(ws + o * 512);
    const float4 w0 = wr[lane * 2], w1 = wr[lane * 2 + 1];
    float p = a0.x * w0.x + a0.y * w0.y + a0.z * w0.z + a0.w * w0.w
            + a1.x * w1.x + a1.y * w1.y + a1.z * w1.z + a1.w * w1.w;
#pragma unroll
    for (int j = 1; j < 64; j <<= 1) p += __shfl_xor(p, j);
    if (lane == 0) out[(size_t)row * 13 + o] = p + cbs[o];
  }
}

} // namespace

extern "C" void kernel_launch(void* const* d_in, const int* in_sizes, int n_in,
                              void* d_out, int out_size, void* d_ws, size_t ws_size,
                              hipStream_t stream)
{
  const float* vertices = (const float*)d_in[0];
  const int*   sidx1    = (const int*)  d_in[1];
  const int*   sidx2    = (const int*)  d_in[2];
  const float* dir0     = (const float*)d_in[3];
  const float* w1 = (const float*)d_in[4];
  const float* b1 = (const float*)d_in[5];
  const float* d1 = (const float*)d_in[6];
  const float* w2 = (const float*)d_in[7];
  const float* b2 = (const float*)d_in[8];
  const float* d2 = (const float*)d_in[9];
  const float* w3 = (const float*)d_in[10];
  const float* b3 = (const float*)d_in[11];
  const float* d3 = (const float*)d_in[12];
  const float* w4 = (const float*)d_in[13];
  const float* b4 = (const float*)d_in[14];
  const float* d4 = (const float*)d_in[15];
  const float* cw1 = (const float*)d_in[16];
  const float* cb1 = (const float*)d_in[17];
  const float* cw2 = (const float*)d_in[18];
  const float* cb2 = (const float*)d_in[19];
  const float* cw3 = (const float*)d_in[20];
  const float* cb3 = (const float*)d_in[21];
  (void)in_sizes; (void)n_in; (void)out_size; (void)ws_size;

  char* ws = (char*)d_ws;
  size_t off = 0;
  auto alloc = [&](size_t bytes) -> void* {
    void* p = ws + off;
    off += (bytes + 255) & ~(size_t)255;
    return p;
  };

  int*   nb1   = (int*)  alloc((size_t)B_ * N0 * 32 * 4);
  int*   nb2   = (int*)  alloc((size_t)B_ * N1 * 32 * 4);
  int*   nb3   = (int*)  alloc((size_t)B_ * N2 * 32 * 4);
  float* vp1   = (float*)alloc((size_t)B_ * N1 * 3 * 4);
  float* vp2   = (float*)alloc((size_t)B_ * N2 * 3 * 4);
  int*   near1 = (int*)  alloc((size_t)B_ * N0 * 4);
  int*   near2 = (int*)  alloc((size_t)B_ * N0 * 4);
  float* h2    = (float*)alloc((size_t)B_ * N0 * 512 * 4);   // 32 MB
  float* fbuf  = (float*)alloc((size_t)B_ * N0 * 256 * 4);   // 16 MB

  const size_t nF0 = (size_t)B_ * N0 * 128;   // fm0 / fm1
  const size_t nP1 = (size_t)B_ * N1 * 128;   // fmp1
  const size_t nF2 = (size_t)B_ * N1 * 256;   // fm2 / fm3
  const size_t nP2 = (size_t)B_ * N2 * 256;   // fmp2
  const size_t nF4 = (size_t)B_ * N2 * 512;
  const size_t nFg = (size_t)B_ * 512;
  const size_t nW1 = (size_t)512 * 1792;
  const size_t nW2 = (size_t)512 * 512;
  const size_t nH1 = (size_t)B_ * N0 * 512;
  ushort_t* f0h = (ushort_t*)alloc(nF0 * 2); ushort_t* f0l = (ushort_t*)alloc(nF0 * 2);
  ushort_t* f1h = (ushort_t*)alloc(nF0 * 2); ushort_t* f1l = (ushort_t*)alloc(nF0 * 2);
  ushort_t* p1h = (ushort_t*)alloc(nP1 * 2); ushort_t* p1l = (ushort_t*)alloc(nP1 * 2);
  ushort_t* f2h = (ushort_t*)alloc(nF2 * 2); ushort_t* f2l = (ushort_t*)alloc(nF2 * 2);
  ushort_t* f3h = (ushort_t*)alloc(nF2 * 2); ushort_t* f3l = (ushort_t*)alloc(nF2 * 2);
  ushort_t* p2h = (ushort_t*)alloc(nP2 * 2); ushort_t* p2l = (ushort_t*)alloc(nP2 * 2);
  ushort_t* f4h = (ushort_t*)alloc(nF4 * 2); ushort_t* f4l = (ushort_t*)alloc(nF4 * 2);
  ushort_t* fgh = (ushort_t*)alloc(nFg * 2); ushort_t* fgl = (ushort_t*)alloc(nFg * 2);
  ushort_t* w1h = (ushort_t*)alloc(nW1 * 2); ushort_t* w1l = (ushort_t*)alloc(nW1 * 2);
  ushort_t* w2h = (ushort_t*)alloc(nW2 * 2); ushort_t* w2l = (ushort_t*)alloc(nW2 * 2);
  ushort_t* h1h = (ushort_t*)alloc(nH1 * 2); ushort_t* h1l = (ushort_t*)alloc(nH1 * 2);
  ushort_t* w1th = (ushort_t*)alloc((size_t)256 * 128 * 2);
  ushort_t* w1tl = (ushort_t*)alloc((size_t)256 * 128 * 2);
  ushort_t* w2th = (ushort_t*)alloc((size_t)512 * 128 * 2);
  ushort_t* w2tl = (ushort_t*)alloc((size_t)512 * 128 * 2);
  ushort_t* w3th = (ushort_t*)alloc((size_t)512 * 256 * 2);
  ushort_t* w3tl = (ushort_t*)alloc((size_t)512 * 256 * 2);
  ushort_t* w4th = (ushort_t*)alloc((size_t)1024 * 256 * 2);
  ushort_t* w4tl = (ushort_t*)alloc((size_t)1024 * 256 * 2);

  const dim3 blk256(256), blk512(512);
  auto mgemm = [&](const ushort_t* Ah, const ushort_t* Al,
                   const ushort_t* Bh, const ushort_t* Bl, const float* bias,
                   int M, int Nn, int K, float* outF) {
    const dim3 grid(Nn / 128, M / 128);
    mfma_gemm_kernel<false, false, false><<<grid, blk256, 0, stream>>>(
        Ah, Al, nullptr, nullptr, nullptr, nullptr, nullptr, nullptr, nullptr,
        nullptr, nullptr, nullptr, nullptr, nullptr, nullptr, nullptr,
        Bh, Bl, bias, K, outF, nullptr, nullptr, Nn);
  };

  // ---- prep: weights + vp1/vp2 in one dispatch ----
  prep_kernel<<<dim3(6588), blk256, 0, stream>>>(
      w1, w2, w3, w4, cw1, cw2, vertices, sidx1, sidx2,
      w1th, w1tl, w2th, w2tl, w3th, w3tl, w4th, w4tl,
      w1h, w1l, w2h, w2l, vp1, vp2);

  // ---- mega: 3 KNN levels + inline fm0 + both nearest argmins ----
  mega_kernel<<<dim3(6784), blk512, 0, stream>>>(
      vertices, vp1, vp2, dir0, nb1, nb2, nb3, f0h, f0l, near1, near2);

  // ---- level 0 (4096 verts) ----
  mgemm(f0h, f0l, w1th, w1tl, b1, B_ * N0, 256, 128, fbuf);
  conv_combine_kernel<<<dim3(B_ * N0), dim3(128), 0, stream>>>(
      fbuf, nb1, d1, vertices, N0, 128, 1, f1h, f1l);

  // ---- pool 1 -> 1024 (top-4 = first 4 of nb1 rows at sidx1) ----
  pool_kernel<<<dim3((B_ * N1 * 128 + 255) / 256), blk256, 0, stream>>>(
      f1h, f1l, nb1, sidx1, N1, N0, 128, p1h, p1l);

  // ---- level 1 (1024 verts) ----
  mgemm(p1h, p1l, w2th, w2tl, b2, B_ * N1, 512, 128, fbuf);
  conv_combine_kernel<<<dim3(B_ * N1), dim3(256), 0, stream>>>(
      fbuf, nb2, d2, vp1, N1, 256, 1, f2h, f2l);
  mgemm(f2h, f2l, w3th, w3tl, b3, B_ * N1, 512, 256, fbuf);
  conv_combine_kernel<<<dim3(B_ * N1), dim3(256), 0, stream>>>(
      fbuf, nb2, d3, vp1, N1, 256, 1, f3h, f3l);

  // ---- pool 2 -> 256 ----
  pool_kernel<<<dim3((B_ * N2 * 256 + 255) / 256), blk256, 0, stream>>>(
      f3h, f3l, nb2, sidx2, N2, N1, 256, p2h, p2l);

  // ---- level 2 (256 verts) ----
  mgemm(p2h, p2l, w4th, w4tl, b4, B_ * N2, 1024, 256, fbuf);
  conv_combine_kernel<<<dim3(B_ * N2), dim3(512), 0, stream>>>(
      fbuf, nb3, d4, vp2, N2, 512, 0, f4h, f4l);     // no relu on fm_4
  global_max_kernel<<<dim3(B_ * 8), blk256, 0, stream>>>(f4h, f4l, fgh, fgl);

  // ---- head MLP ----
  mfma_gemm_kernel<true, true, true><<<dim3(512 / 128, (B_ * N0) / 128), blk256, 0, stream>>>(
      nullptr, nullptr,
      f0h, f0l, f1h, f1l, f2h, f2l, f3h, f3l, f4h, f4l, fgh, fgl,
      near1, near2, w1h, w1l, cb1, 1792, nullptr, h1h, h1l, 512);
  mfma_gemm_kernel<false, false, true><<<dim3(512 / 128, (B_ * N0) / 128), blk256, 0, stream>>>(
      h1h, h1l,
      nullptr, nullptr, nullptr, nullptr, nullptr, nullptr, nullptr, nullptr,
      nullptr, nullptr, nullptr, nullptr,
      nullptr, nullptr, w2h, w2l, cb2, 512, h2, nullptr, nullptr, 512);
  head_wave_kernel<<<dim3((B_ * N0) / 4), blk256, 0, stream>>>(
      h2, cw3, cb3, (float*)d_out);
}

// Round 17
// 573.242 us; speedup vs baseline: 1.0150x; 1.0130x over previous
//
#include <hip/hip_runtime.h>
#include <cstdint>
#include <cstddef>

namespace {

typedef unsigned short ushort_t;
typedef __bf16 bf16x8 __attribute__((ext_vector_type(8)));
typedef float  f32x4  __attribute__((ext_vector_type(4)));

constexpr int B_ = 4;
constexpr int N0 = 4096;   // vertices per batch
constexpr int N1 = 1024;   // after pool1
constexpr int N2 = 256;    // after pool2

// ----------------------------------------------------- bf16 split utils ----
__device__ __forceinline__ ushort_t f2bf_rne(float x) {
  uint32_t b = __float_as_uint(x);
  b += 0x7FFFu + ((b >> 16) & 1u);
  return (ushort_t)(b >> 16);
}
__device__ __forceinline__ float bf2f(ushort_t h) {
  return __uint_as_float(((uint32_t)h) << 16);
}
__device__ __forceinline__ void split_store(float x, ushort_t* hi, ushort_t* lo,
                                            size_t i) {
  const ushort_t h = f2bf_rne(x);
  hi[i] = h;
  lo[i] = f2bf_rne(x - bf2f(h));
}

// ------------------- fused prep: weight split/transpose + vp1/vp2 gather ---
__global__ void prep_kernel(
    const float* __restrict__ w1, const float* __restrict__ w2,
    const float* __restrict__ w3, const float* __restrict__ w4,
    const float* __restrict__ cw1, const float* __restrict__ cw2,
    const float* __restrict__ vertices,
    const int* __restrict__ sidx1, const int* __restrict__ sidx2,
    ushort_t* __restrict__ w1th, ushort_t* __restrict__ w1tl,
    ushort_t* __restrict__ w2th, ushort_t* __restrict__ w2tl,
    ushort_t* __restrict__ w3th, ushort_t* __restrict__ w3tl,
    ushort_t* __restrict__ w4th, ushort_t* __restrict__ w4tl,
    ushort_t* __restrict__ w1h, ushort_t* __restrict__ w1l,
    ushort_t* __restrict__ w2h, ushort_t* __restrict__ w2l,
    float* __restrict__ vp1, float* __restrict__ vp2)
{
  const int i = blockIdx.x * blockDim.x + threadIdx.x;
  if (i < 32768) {                       // w1: K=128, N=256
    const int j = i, k = j % 128, n = j / 128;
    split_store(w1[(size_t)k * 256 + n], w1th, w1tl, (size_t)n * 128 + k);
  } else if (i < 98304) {                // w2: K=128, N=512
    const int j = i - 32768, k = j % 128, n = j / 128;
    split_store(w2[(size_t)k * 512 + n], w2th, w2tl, (size_t)n * 128 + k);
  } else if (i < 229376) {               // w3: K=256, N=512
    const int j = i - 98304, k = j % 256, n = j / 256;
    split_store(w3[(size_t)k * 512 + n], w3th, w3tl, (size_t)n * 256 + k);
  } else if (i < 491520) {               // w4: K=256, N=1024
    const int j = i - 229376, k = j % 256, n = j / 256;
    split_store(w4[(size_t)k * 1024 + n], w4th, w4tl, (size_t)n * 256 + k);
  } else if (i < 1409024) {              // cw1: already (N,K)
    const int j = i - 491520;
    split_store(cw1[j], w1h, w1l, j);
  } else if (i < 1671168) {              // cw2
    const int j = i - 1409024;
    split_store(cw2[j], w2h, w2l, j);
  } else if (i < 1683456) {              // vp1 = vertices[:, sidx1, :]
    const int j = i - 1671168;
    const int c = j % 3, q = (j / 3) % N1, b = j / (3 * N1);
    vp1[j] = vertices[((size_t)b * N0 + sidx1[q]) * 3 + c];
  } else if (i < 1686528) {              // vp2 = vertices[:, sidx1[sidx2], :]
    const int j = i - 1683456;
    const int c = j % 3, q = (j / 3) % N2, b = j / (3 * N2);
    vp2[j] = vertices[((size_t)b * N0 + sidx1[sidx2[q]]) * 3 + c];
  }
}

// ------------------------------------------------- wave-cooperative KNN ----
__device__ __forceinline__ void bitonic_sort64(float& sd, int& si, int lane) {
#pragma unroll
  for (int kk = 2; kk <= 64; kk <<= 1) {
#pragma unroll
    for (int j = kk >> 1; j > 0; j >>= 1) {
      const float od = __shfl_xor(sd, j);
      const int   oi = __shfl_xor(si, j);
      const bool less    = (sd < od) || (sd == od && si < oi);
      const bool wantMin = ((lane & j) == 0) == ((lane & kk) == 0);
      if (wantMin != less) { sd = od; si = oi; }
    }
  }
}

__device__ __forceinline__ void knn_flush(float& ld, int& li, float& tau,
                                          int cnt, const float* bufd,
                                          const int* bufi, int lane, int Km1) {
  float sd = (lane < cnt) ? bufd[lane] : INFINITY;
  int   si = (lane < cnt) ? bufi[lane] : 0x7fffffff;
  bitonic_sort64(sd, si, lane);
  const float rd = __shfl(sd, 63 - lane);
  const int   ri = __shfl(si, 63 - lane);
  const bool keep = (ld < rd) || (ld == rd && li < ri);
  float md = keep ? ld : rd;
  int   mi = keep ? li : ri;
#pragma unroll
  for (int j = 32; j > 0; j >>= 1) {
    const float od = __shfl_xor(md, j);
    const int   oi = __shfl_xor(mi, j);
    const bool less    = (md < od) || (md == od && mi < oi);
    const bool wantMin = ((lane & j) == 0);
    if (wantMin != less) { md = od; mi = oi; }
  }
  ld = md; li = mi;
  tau = __shfl(ld, Km1);
}

// MEGA kernel: 3 KNN levels + inline fm0 (conv_surface) + both nearest
// argmins, one dispatch (proven round-15 config).
__launch_bounds__(512)
__global__ void mega_kernel(const float* __restrict__ verts,
                            const float* __restrict__ vp1,
                            const float* __restrict__ vp2,
                            const float* __restrict__ dir,   // (3,128)
                            int* __restrict__ nb1,
                            int* __restrict__ nb2,
                            int* __restrict__ nb3,
                            ushort_t* __restrict__ f0h,
                            ushort_t* __restrict__ f0l,
                            int* __restrict__ near1,
                            int* __restrict__ near2)
{
  constexpr int K = 32, TILE = 2048;
  __shared__ float4 sp[TILE];
  __shared__ float sbd[8][64];
  __shared__ int   sbi[8][64];

  int bx = blockIdx.x;
  const int lane = threadIdx.x & 63;
  const int wid  = threadIdx.x >> 6;

  if (bx >= 2688) {
    // ---------------- nearest segment ----------------
    const int seg = bx - 2688;
    const int lvl = seg >> 11;             // 2048 blocks per level
    const int sb  = seg & 2047;
    const int C   = lvl ? N2 : N1;
    const float* cpts = lvl ? vp2 : vp1;
    int* out = lvl ? near2 : near1;
    const int q = sb * 8 + wid;            // over B_*N0
    const int b = q >> 12;
    const float qx = verts[(size_t)q * 3 + 0];
    const float qy = verts[(size_t)q * 3 + 1];
    const float qz = verts[(size_t)q * 3 + 2];
    const float q2   = qx * qx + qy * qy + qz * qz;
    const float m2qx = -2.0f * qx, m2qy = -2.0f * qy, m2qz = -2.0f * qz;
    const float* pb = cpts + (size_t)b * C * 3;
    for (int i = threadIdx.x; i < C; i += 512) {
      const float x = pb[i * 3 + 0];
      const float y = pb[i * 3 + 1];
      const float z = pb[i * 3 + 2];
      sp[i] = make_float4(x, y, z, x * x + y * y + z * z);
    }
    __syncthreads();
    float best = INFINITY; int bi = 0x7fffffff;
    for (int base = 0; base < C; base += 64) {
      const float4 p = sp[base + lane];
      const float d = fmaf(m2qx, p.x, fmaf(m2qy, p.y, fmaf(m2qz, p.z, p.w + q2)));
      if (d < best) { best = d; bi = base + lane; }
    }
#pragma unroll
    for (int j = 1; j < 64; j <<= 1) {
      const float od = __shfl_xor(best, j);
      const int   oi = __shfl_xor(bi, j);
      if (od < best || (od == best && oi < bi)) { best = od; bi = oi; }
    }
    if (lane == 0) out[q] = bi;
    return;
  }

  // ---------------- KNN segment ----------------
  const float* pts; int Q, C; int* out; bool isL0 = false;
  if (bx < 2048)      { pts = verts; Q = N0; C = N0; out = nb1; isL0 = true; }
  else if (bx < 2560) { pts = vp1;   Q = N1; C = N1; out = nb2; bx -= 2048; }
  else                { pts = vp2;   Q = N2; C = N2; out = nb3; bx -= 2560; }
  const int bpb = Q / 8;
  const int b  = bx / bpb;
  const int q    = (bx % bpb) * 8 + wid;
  const int self = q;
  const float* pb = pts + (size_t)b * C * 3;
  const float qx = pb[self * 3 + 0];
  const float qy = pb[self * 3 + 1];
  const float qz = pb[self * 3 + 2];
  const float q2   = qx * qx + qy * qy + qz * qz;
  const float m2qx = -2.0f * qx, m2qy = -2.0f * qy, m2qz = -2.0f * qz;

  float ld = INFINITY; int li = 0x7fffffff;
  float tau = INFINITY;
  int cnt = 0;
  float* bufd = sbd[wid];
  int*   bufi = sbi[wid];

  auto append = [&](unsigned long long m, bool cand, float d, int ci) {
    const int c = __popcll(m);
    if (cnt + c > 64) {
      knn_flush(ld, li, tau, cnt, bufd, bufi, lane, K - 1);
      cnt = 0;
    }
    const int prefix = __popcll(m & ((1ull << lane) - 1ull));
    if (cand) { bufd[cnt + prefix] = d; bufi[cnt + prefix] = ci; }
    cnt += c;
  };

  for (int t0 = 0; t0 < C; t0 += TILE) {
    const int nt = (C - t0 < TILE) ? (C - t0) : TILE;
    __syncthreads();
    for (int i = threadIdx.x; i < nt; i += 512) {
      const float x = pb[(t0 + i) * 3 + 0];
      const float y = pb[(t0 + i) * 3 + 1];
      const float z = pb[(t0 + i) * 3 + 2];
      sp[i] = make_float4(x, y, z, x * x + y * y + z * z);
    }
    __syncthreads();
    int base = 0;
    if (t0 == 0) {
      const float4 p = sp[lane];
      const float d = fmaf(m2qx, p.x, fmaf(m2qy, p.y, fmaf(m2qz, p.z, p.w + q2)));
      const bool valid = (lane != self);
      float sd = valid ? d : INFINITY;
      int   si = valid ? lane : 0x7fffffff;
      bitonic_sort64(sd, si, lane);
      ld = sd; li = si;
      tau = __shfl(ld, K - 1);
      base = 64;
    }
    for (; base + 128 <= nt; base += 128) {
      const int ci0 = t0 + base + lane;
      const int ci1 = ci0 + 64;
      const float4 p0 = sp[base + lane];
      const float4 p1 = sp[base + 64 + lane];
      const float d0 = fmaf(m2qx, p0.x, fmaf(m2qy, p0.y, fmaf(m2qz, p0.z, p0.w + q2)));
      const float d1 = fmaf(m2qx, p1.x, fmaf(m2qy, p1.y, fmaf(m2qz, p1.z, p1.w + q2)));
      const bool c0 = (ci0 != self) && (d0 < tau);
      const bool c1 = (ci1 != self) && (d1 < tau);
      const unsigned long long m0 = __ballot(c0);
      const unsigned long long m1 = __ballot(c1);
      if (m0) append(m0, c0, d0, ci0);
      if (m1) append(m1, c1, d1, ci1);
    }
    if (base < nt) {
      const int ci = t0 + base + lane;
      const float4 p = sp[base + lane];
      const float d = fmaf(m2qx, p.x, fmaf(m2qy, p.y, fmaf(m2qz, p.z, p.w + q2)));
      const bool c = (ci != self) && (d < tau);
      const unsigned long long m = __ballot(c);
      if (m) append(m, c, d, ci);
    }
  }
  if (cnt > 0) knn_flush(ld, li, tau, cnt, bufd, bufi, lane, K - 1);
  if (lane < K) out[((size_t)b * Q + q) * K + lane] = li;

  if (isL0) {
    // ---- inline conv_surface: fm0 from the in-register top-32 ----
    float ux = 0.f, uy = 0.f, uz = 0.f;
    if (lane < 32) {
      const float dx = pb[li * 3 + 0] - qx;
      const float dy = pb[li * 3 + 1] - qy;
      const float dz = pb[li * 3 + 2] - qz;
      const float rn = 1.0f / fmaxf(sqrtf(dx * dx + dy * dy + dz * dz), 1e-12f);
      ux = dx * rn; uy = dy * rn; uz = dz * rn;
    }
    const int o1 = lane, o2 = lane + 64;
    float d0a = dir[o1], d1a = dir[128 + o1], d2a = dir[256 + o1];
    const float rna = 1.0f / fmaxf(sqrtf(d0a*d0a + d1a*d1a + d2a*d2a), 1e-12f);
    d0a *= rna; d1a *= rna; d2a *= rna;
    float d0b = dir[o2], d1b = dir[128 + o2], d2b = dir[256 + o2];
    const float rnb = 1.0f / fmaxf(sqrtf(d0b*d0b + d1b*d1b + d2b*d2b), 1e-12f);
    d0b *= rnb; d1b *= rnb; d2b *= rnb;
    float ma = -INFINITY, mb = -INFINITY;
#pragma unroll 8
    for (int n = 0; n < 32; ++n) {
      const float nx = __shfl(ux, n);
      const float ny = __shfl(uy, n);
      const float nz = __shfl(uz, n);
      const float ta = fmaxf(0.0f, fmaf(d2a, nz, fmaf(d1a, ny, d0a * nx)));
      const float tb = fmaxf(0.0f, fmaf(d2b, nz, fmaf(d1b, ny, d0b * nx)));
      ma = fmaxf(ma, ta); mb = fmaxf(mb, tb);
    }
    const size_t baseo = ((size_t)b * N0 + q) * 128;
    split_store(fmaxf(0.0f, ma), f0h, f0l, baseo + o1);
    split_store(fmaxf(0.0f, mb), f0h, f0l, baseo + o2);
  }
}

// -------------------------------------------------------- conv_combine -----
__global__ void conv_combine_kernel(const float* __restrict__ f,    // (B,V,2C)
                                    const int*   __restrict__ nb,
                                    const float* __restrict__ dir,
                                    const float* __restrict__ verts,
                                    int V, int C, int relu,
                                    ushort_t* __restrict__ outH,
                                    ushort_t* __restrict__ outL) {
  __shared__ float ux[32], uy[32], uz[32];
  __shared__ int snb[32];
  const int bv = blockIdx.x;
  const int b = bv / V;
  const int v = bv - b * V;
  const float* vb = verts + (size_t)b * V * 3;
  if (threadIdx.x < 32) {
    const float cx = vb[v * 3 + 0], cy = vb[v * 3 + 1], cz = vb[v * 3 + 2];
    const int nidx = nb[(size_t)bv * 32 + threadIdx.x];
    snb[threadIdx.x] = nidx;
    const float dx = vb[nidx * 3 + 0] - cx;
    const float dy = vb[nidx * 3 + 1] - cy;
    const float dz = vb[nidx * 3 + 2] - cz;
    const float rn = 1.0f / fmaxf(sqrtf(dx * dx + dy * dy + dz * dz), 1e-12f);
    ux[threadIdx.x] = dx * rn; uy[threadIdx.x] = dy * rn; uz[threadIdx.x] = dz * rn;
  }
  __syncthreads();
  const int o = threadIdx.x;
  float d0 = dir[o], d1 = dir[C + o], d2 = dir[2 * C + o];
  const float rn = 1.0f / fmaxf(sqrtf(d0 * d0 + d1 * d1 + d2 * d2), 1e-12f);
  d0 *= rn; d1 *= rn; d2 *= rn;
  const float* fb = f + (size_t)b * V * 2 * C;
  float m = -INFINITY;
#pragma unroll 8
  for (int n = 0; n < 32; ++n) {
    const float t = fmaxf(0.0f, fmaf(d2, uz[n], fmaf(d1, uy[n], d0 * ux[n])));
    const float s = fb[(size_t)snb[n] * 2 * C + C + o];
    m = fmaxf(m, t * s);
  }
  float r = fb[(size_t)v * 2 * C + o] + m;
  if (relu) r = fmaxf(r, 0.0f);
  split_store(r, outH, outL, (size_t)bv * C + o);
}

// ---------------------------------------------------------------- pool -----
__global__ void pool_kernel(const ushort_t* __restrict__ fmH,
                            const ushort_t* __restrict__ fmL,
                            const int*   __restrict__ nb,   // (B, Vsrc, 32)
                            const int*   __restrict__ sidx, // (Q,)
                            int Q, int Vsrc, int C,
                            ushort_t* __restrict__ outH,
                            ushort_t* __restrict__ outL) {
  const int i = blockIdx.x * blockDim.x + threadIdx.x;
  if (i >= B_ * Q * C) return;
  const int c = i % C;
  const int q = (i / C) % Q;
  const int b = i / (C * Q);
  const int* nn = nb + ((size_t)b * Vsrc + sidx[q]) * 32;
  const size_t fb = (size_t)b * Vsrc * C;
  float m = -INFINITY;
#pragma unroll
  for (int t = 0; t < 4; ++t) {
    const size_t idx = fb + (size_t)nn[t] * C + c;
    m = fmaxf(m, bf2f(fmH[idx]) + bf2f(fmL[idx]));
  }
  split_store(m, outH, outL, (size_t)i);
}

// grid = B_*8 blocks of 256 thr: 64 channels x 4 v-slices per block
__global__ void global_max_kernel(const ushort_t* __restrict__ fmH,
                                  const ushort_t* __restrict__ fmL,
                                  ushort_t* __restrict__ outH,
                                  ushort_t* __restrict__ outL) {
  __shared__ float red[4][64];
  const int t = threadIdx.x;
  const int cl = t & 63, slice = t >> 6;
  const int c = (blockIdx.x & 7) * 64 + cl;
  const int b = blockIdx.x >> 3;
  const size_t base = (size_t)b * 256 * 512 + c;
  float m = -INFINITY;
  for (int v = slice; v < 256; v += 4) {
    const size_t idx = base + (size_t)v * 512;
    m = fmaxf(m, bf2f(fmH[idx]) + bf2f(fmL[idx]));
  }
  red[slice][cl] = m;
  __syncthreads();
  if (slice == 0) {
    m = fmaxf(fmaxf(red[0][cl], red[1][cl]), fmaxf(red[2][cl], red[3][cl]));
    split_store(m, outH, outL, (size_t)b * 512 + c);
  }
}

// ------------------------------------------- split-bf16 MFMA GEMM ----------
constexpr int LDT = 36;  // LDS row stride in ushorts (32 + 4 pad)

// 128M x 128N tile (head GEMMs; big-K: best LDS-bytes-per-FLOP)
template<bool FUSE, bool SPLITOUT, bool RELU>
__launch_bounds__(256)
__global__ void mfma_gemm_kernel(
    const ushort_t* __restrict__ Ahi, const ushort_t* __restrict__ Alo,
    const ushort_t* __restrict__ f0h, const ushort_t* __restrict__ f0l,
    const ushort_t* __restrict__ f1h, const ushort_t* __restrict__ f1l,
    const ushort_t* __restrict__ f2h, const ushort_t* __restrict__ f2l,
    const ushort_t* __restrict__ f3h, const ushort_t* __restrict__ f3l,
    const ushort_t* __restrict__ f4h, const ushort_t* __restrict__ f4l,
    const ushort_t* __restrict__ fgh, const ushort_t* __restrict__ fgl,
    const int* __restrict__ near1, const int* __restrict__ near2,
    const ushort_t* __restrict__ Bhi, const ushort_t* __restrict__ Blo,
    const float* __restrict__ bias, int K,
    float* __restrict__ outF, ushort_t* __restrict__ outHi,
    ushort_t* __restrict__ outLo, int Nn)
{
  __shared__ ushort_t As_h[128 * LDT];
  __shared__ ushort_t As_l[128 * LDT];
  __shared__ ushort_t Bs_h[128 * LDT];
  __shared__ ushort_t Bs_l[128 * LDT];

  const int tid  = threadIdx.x;
  const int lane = tid & 63;
  const int wv   = tid >> 6;
  const int wr   = wv >> 1, wc = wv & 1;
  const int quad = lane >> 4, ml = lane & 15;
  const int m0 = blockIdx.y * 128, n0 = blockIdx.x * 128;

  const int r  = tid >> 1;         // staging row 0..127
  const int hh = (tid & 1) * 16;   // 16-elem half of BK=32

  int fb = 0, r1 = 0, r2 = 0;
  if (FUSE) {
    const int m = m0 + r;
    fb = m >> 12;                  // / 4096
    r1 = near1[m];
    r2 = near2[m];
  }

  uint4 a0h, a1h, a0l, a1l, b0h, b1h, b0l, b1l;
  auto load_slice = [&](int k0) {
    const int k = k0 + hh;
    {
      const ushort_t *sh, *sl; size_t off;
      if (FUSE) {
        const int m = m0 + r;
        if (k < 128)       { sh = f0h; sl = f0l; off = (size_t)m * 128 + k; }
        else if (k < 256)  { sh = f1h; sl = f1l; off = (size_t)m * 128 + (k - 128); }
        else if (k < 512)  { sh = f2h; sl = f2l; off = ((size_t)fb * 1024 + r1) * 256 + (k - 256); }
        else if (k < 768)  { sh = f3h; sl = f3l; off = ((size_t)fb * 1024 + r1) * 256 + (k - 512); }
        else if (k < 1280) { sh = f4h; sl = f4l; off = ((size_t)fb * 256 + r2) * 512 + (k - 768); }
        else               { sh = fgh; sl = fgl; off = (size_t)fb * 512 + (k - 1280); }
      } else {
        sh = Ahi; sl = Alo; off = (size_t)(m0 + r) * K + k;
      }
      a0h = *(const uint4*)(sh + off); a1h = *(const uint4*)(sh + off + 8);
      a0l = *(const uint4*)(sl + off); a1l = *(const uint4*)(sl + off + 8);
    }
    {
      const size_t off = (size_t)(n0 + r) * K + k;
      b0h = *(const uint4*)(Bhi + off); b1h = *(const uint4*)(Bhi + off + 8);
      b0l = *(const uint4*)(Blo + off); b1l = *(const uint4*)(Blo + off + 8);
    }
  };

  f32x4 acc[4][4];
#pragma unroll
  for (int i = 0; i < 4; ++i)
#pragma unroll
    for (int j = 0; j < 4; ++j) acc[i][j] = f32x4{0.f, 0.f, 0.f, 0.f};

  load_slice(0);
  for (int k0 = 0; k0 < K; k0 += 32) {
    __syncthreads();
    *(uint4*)&As_h[r * LDT + hh]     = a0h;
    *(uint4*)&As_h[r * LDT + hh + 8] = a1h;
    *(uint4*)&As_l[r * LDT + hh]     = a0l;
    *(uint4*)&As_l[r * LDT + hh + 8] = a1l;
    *(uint4*)&Bs_h[r * LDT + hh]     = b0h;
    *(uint4*)&Bs_h[r * LDT + hh + 8] = b1h;
    *(uint4*)&Bs_l[r * LDT + hh]     = b0l;
    *(uint4*)&Bs_l[r * LDT + hh + 8] = b1l;
    __syncthreads();
    if (k0 + 32 < K) load_slice(k0 + 32);   // prefetch overlaps MFMAs below

    bf16x8 ah[4], al[4], bh[4], bl[4];
#pragma unroll
    for (int i = 0; i < 4; ++i) {
      const int row = wr * 64 + i * 16 + ml;
      ah[i] = *(const bf16x8*)&As_h[row * LDT + quad * 8];
      al[i] = *(const bf16x8*)&As_l[row * LDT + quad * 8];
    }
#pragma unroll
    for (int j = 0; j < 4; ++j) {
      const int row = wc * 64 + j * 16 + ml;
      bh[j] = *(const bf16x8*)&Bs_h[row * LDT + quad * 8];
      bl[j] = *(const bf16x8*)&Bs_l[row * LDT + quad * 8];
    }
#pragma unroll
    for (int i = 0; i < 4; ++i)
#pragma unroll
      for (int j = 0; j < 4; ++j) {
        acc[i][j] = __builtin_amdgcn_mfma_f32_16x16x32_bf16(al[i], bh[j], acc[i][j], 0, 0, 0);
        acc[i][j] = __builtin_amdgcn_mfma_f32_16x16x32_bf16(ah[i], bl[j], acc[i][j], 0, 0, 0);
        acc[i][j] = __builtin_amdgcn_mfma_f32_16x16x32_bf16(ah[i], bh[j], acc[i][j], 0, 0, 0);
      }
  }

  // epilogue: C/D mapping col=lane&15, row=quad*4+reg (m89)
#pragma unroll
  for (int i = 0; i < 4; ++i)
#pragma unroll
    for (int j = 0; j < 4; ++j) {
      const int n = n0 + wc * 64 + j * 16 + ml;
      const float bv = bias[n];
#pragma unroll
      for (int reg = 0; reg < 4; ++reg) {
        const int m = m0 + wr * 64 + i * 16 + quad * 4 + reg;
        float r = acc[i][j][reg] + bv;
        if (RELU) r = fmaxf(r, 0.0f);
        if (SPLITOUT) {
          const ushort_t h = f2bf_rne(r);
          outHi[(size_t)m * Nn + n] = h;
          outLo[(size_t)m * Nn + n] = f2bf_rne(r - bf2f(h));
        } else {
          outF[(size_t)m * Nn + n] = r;
        }
      }
    }
}

// 64M x 128N tile (conv GEMMs: small K, grid-starved at 128-tile — conv2/3
// were 128 blocks = 0.5 blocks/CU. Round-4-proven staging layout, LDT=36).
__launch_bounds__(256)
__global__ void mfma_gemm64_kernel(
    const ushort_t* __restrict__ Ahi, const ushort_t* __restrict__ Alo,
    const ushort_t* __restrict__ Bhi, const ushort_t* __restrict__ Blo,
    const float* __restrict__ bias, int K,
    float* __restrict__ outF, int Nn)
{
  __shared__ ushort_t As_h[64 * LDT];
  __shared__ ushort_t As_l[64 * LDT];
  __shared__ ushort_t Bs_h[128 * LDT];
  __shared__ ushort_t Bs_l[128 * LDT];

  const int tid  = threadIdx.x;
  const int lane = tid & 63;
  const int wv   = tid >> 6;
  const int wr   = wv >> 1, wc = wv & 1;
  const int quad = lane >> 4, ml = lane & 15;
  const int m0 = blockIdx.y * 64, n0 = blockIdx.x * 128;

  const int ar = tid >> 2;         // staging row 0..63 (A; B rows ar, 64+ar)
  const int s8 = (tid & 3) * 8;    // 8-elem chunk within BK=32

  uint4 avh, avl, bvh0, bvl0, bvh1, bvl1;
  auto load_slice = [&](int k0) {
    const int k = k0 + s8;
    {
      const size_t off = (size_t)(m0 + ar) * K + k;
      avh = *(const uint4*)(Ahi + off);
      avl = *(const uint4*)(Alo + off);
    }
    {
      const size_t off0 = (size_t)(n0 + ar) * K + k;
      const size_t off1 = (size_t)(n0 + 64 + ar) * K + k;
      bvh0 = *(const uint4*)(Bhi + off0);
      bvl0 = *(const uint4*)(Blo + off0);
      bvh1 = *(const uint4*)(Bhi + off1);
      bvl1 = *(const uint4*)(Blo + off1);
    }
  };

  f32x4 acc[2][4];
#pragma unroll
  for (int i = 0; i < 2; ++i)
#pragma unroll
    for (int j = 0; j < 4; ++j) acc[i][j] = f32x4{0.f, 0.f, 0.f, 0.f};

  load_slice(0);
  for (int k0 = 0; k0 < K; k0 += 32) {
    __syncthreads();
    *(uint4*)&As_h[ar * LDT + s8] = avh;
    *(uint4*)&As_l[ar * LDT + s8] = avl;
    *(uint4*)&Bs_h[ar * LDT + s8] = bvh0;
    *(uint4*)&Bs_l[ar * LDT + s8] = bvl0;
    *(uint4*)&Bs_h[(64 + ar) * LDT + s8] = bvh1;
    *(uint4*)&Bs_l[(64 + ar) * LDT + s8] = bvl1;
    __syncthreads();
    if (k0 + 32 < K) load_slice(k0 + 32);

    bf16x8 ah[2], al[2], bh[4], bl[4];
#pragma unroll
    for (int i = 0; i < 2; ++i) {
      const int row = wr * 32 + i * 16 + ml;
      ah[i] = *(const bf16x8*)&As_h[row * LDT + quad * 8];
      al[i] = *(const bf16x8*)&As_l[row * LDT + quad * 8];
    }
#pragma unroll
    for (int j = 0; j < 4; ++j) {
      const int row = wc * 64 + j * 16 + ml;
      bh[j] = *(const bf16x8*)&Bs_h[row * LDT + quad * 8];
      bl[j] = *(const bf16x8*)&Bs_l[row * LDT + quad * 8];
    }
#pragma unroll
    for (int i = 0; i < 2; ++i)
#pragma unroll
      for (int j = 0; j < 4; ++j) {
        acc[i][j] = __builtin_amdgcn_mfma_f32_16x16x32_bf16(al[i], bh[j], acc[i][j], 0, 0, 0);
        acc[i][j] = __builtin_amdgcn_mfma_f32_16x16x32_bf16(ah[i], bl[j], acc[i][j], 0, 0, 0);
        acc[i][j] = __builtin_amdgcn_mfma_f32_16x16x32_bf16(ah[i], bh[j], acc[i][j], 0, 0, 0);
      }
  }

#pragma unroll
  for (int i = 0; i < 2; ++i)
#pragma unroll
    for (int j = 0; j < 4; ++j) {
      const int n = n0 + wc * 64 + j * 16 + ml;
      const float bv = bias[n];
#pragma unroll
      for (int reg = 0; reg < 4; ++reg) {
        const int m = m0 + wr * 32 + i * 16 + quad * 4 + reg;
        outF[(size_t)m * Nn + n] = acc[i][j][reg] + bv;
      }
    }
}

// --------------------------------------------------- head: wave per row ----
__launch_bounds__(256)
__global__ void head_wave_kernel(const float* __restrict__ h,   // (16384, 512)
                                 const float* __restrict__ cw,  // (13, 512)
                                 const float* __restrict__ cb,  // (13,)
                                 float* __restrict__ out) {     // (16384, 13)
  __shared__ float ws[13 * 512];
  __shared__ float cbs[13];
  const int lane = threadIdx.x & 63;
  const int wid  = threadIdx.x >> 6;
  for (int i = threadIdx.x; i < 13 * 512; i += 256) ws[i] = cw[i];
  if (threadIdx.x < 13) cbs[threadIdx.x] = cb[threadIdx.x];
  __syncthreads();
  const int row = blockIdx.x * 4 + wid;
  const float4* hr = (const float4*)(h + (size_t)row * 512);
  const float4 a0 = hr[lane * 2], a1 = hr[lane * 2 + 1];
#pragma unroll
  for (int o = 0; o < 13; ++o) {
    const float4* wr = (const float4*)(ws + o * 512);
    const float4 w0 = wr[lane * 2], w1 = wr[lane * 2 + 1];
    float p = a0.x * w0.x + a0.y * w0.y + a0.z * w0.z + a0.w * w0.w
            + a1.x * w1.x + a1.y * w1.y + a1.z * w1.z + a1.w * w1.w;
#pragma unroll
    for (int j = 1; j < 64; j <<= 1) p += __shfl_xor(p, j);
    if (lane == 0) out[(size_t)row * 13 + o] = p + cbs[o];
  }
}

} // namespace

extern "C" void kernel_launch(void* const* d_in, const int* in_sizes, int n_in,
                              void* d_out, int out_size, void* d_ws, size_t ws_size,
                              hipStream_t stream)
{
  const float* vertices = (const float*)d_in[0];
  const int*   sidx1    = (const int*)  d_in[1];
  const int*   sidx2    = (const int*)  d_in[2];
  const float* dir0     = (const float*)d_in[3];
  const float* w1 = (const float*)d_in[4];
  const float* b1 = (const float*)d_in[5];
  const float* d1 = (const float*)d_in[6];
  const float* w2 = (const float*)d_in[7];
  const float* b2 = (const float*)d_in[8];
  const float* d2 = (const float*)d_in[9];
  const float* w3 = (const float*)d_in[10];
  const float* b3 = (const float*)d_in[11];
  const float* d3 = (const float*)d_in[12];
  const float* w4 = (const float*)d_in[13];
  const float* b4 = (const float*)d_in[14];
  const float* d4 = (const float*)d_in[15];
  const float* cw1 = (const float*)d_in[16];
  const float* cb1 = (const float*)d_in[17];
  const float* cw2 = (const float*)d_in[18];
  const float* cb2 = (const float*)d_in[19];
  const float* cw3 = (const float*)d_in[20];
  const float* cb3 = (const float*)d_in[21];
  (void)in_sizes; (void)n_in; (void)out_size; (void)ws_size;

  char* ws = (char*)d_ws;
  size_t off = 0;
  auto alloc = [&](size_t bytes) -> void* {
    void* p = ws + off;
    off += (bytes + 255) & ~(size_t)255;
    return p;
  };

  int*   nb1   = (int*)  alloc((size_t)B_ * N0 * 32 * 4);
  int*   nb2   = (int*)  alloc((size_t)B_ * N1 * 32 * 4);
  int*   nb3   = (int*)  alloc((size_t)B_ * N2 * 32 * 4);
  float* vp1   = (float*)alloc((size_t)B_ * N1 * 3 * 4);
  float* vp2   = (float*)alloc((size_t)B_ * N2 * 3 * 4);
  int*   near1 = (int*)  alloc((size_t)B_ * N0 * 4);
  int*   near2 = (int*)  alloc((size_t)B_ * N0 * 4);
  float* h2    = (float*)alloc((size_t)B_ * N0 * 512 * 4);   // 32 MB
  float* fbuf  = (float*)alloc((size_t)B_ * N0 * 256 * 4);   // 16 MB

  const size_t nF0 = (size_t)B_ * N0 * 128;   // fm0 / fm1
  const size_t nP1 = (size_t)B_ * N1 * 128;   // fmp1
  const size_t nF2 = (size_t)B_ * N1 * 256;   // fm2 / fm3
  const size_t nP2 = (size_t)B_ * N2 * 256;   // fmp2
  const size_t nF4 = (size_t)B_ * N2 * 512;
  const size_t nFg = (size_t)B_ * 512;
  const size_t nW1 = (size_t)512 * 1792;
  const size_t nW2 = (size_t)512 * 512;
  const size_t nH1 = (size_t)B_ * N0 * 512;
  ushort_t* f0h = (ushort_t*)alloc(nF0 * 2); ushort_t* f0l = (ushort_t*)alloc(nF0 * 2);
  ushort_t* f1h = (ushort_t*)alloc(nF0 * 2); ushort_t* f1l = (ushort_t*)alloc(nF0 * 2);
  ushort_t* p1h = (ushort_t*)alloc(nP1 * 2); ushort_t* p1l = (ushort_t*)alloc(nP1 * 2);
  ushort_t* f2h = (ushort_t*)alloc(nF2 * 2); ushort_t* f2l = (ushort_t*)alloc(nF2 * 2);
  ushort_t* f3h = (ushort_t*)alloc(nF2 * 2); ushort_t* f3l = (ushort_t*)alloc(nF2 * 2);
  ushort_t* p2h = (ushort_t*)alloc(nP2 * 2); ushort_t* p2l = (ushort_t*)alloc(nP2 * 2);
  ushort_t* f4h = (ushort_t*)alloc(nF4 * 2); ushort_t* f4l = (ushort_t*)alloc(nF4 * 2);
  ushort_t* fgh = (ushort_t*)alloc(nFg * 2); ushort_t* fgl = (ushort_t*)alloc(nFg * 2);
  ushort_t* w1h = (ushort_t*)alloc(nW1 * 2); ushort_t* w1l = (ushort_t*)alloc(nW1 * 2);
  ushort_t* w2h = (ushort_t*)alloc(nW2 * 2); ushort_t* w2l = (ushort_t*)alloc(nW2 * 2);
  ushort_t* h1h = (ushort_t*)alloc(nH1 * 2); ushort_t* h1l = (ushort_t*)alloc(nH1 * 2);
  ushort_t* w1th = (ushort_t*)alloc((size_t)256 * 128 * 2);
  ushort_t* w1tl = (ushort_t*)alloc((size_t)256 * 128 * 2);
  ushort_t* w2th = (ushort_t*)alloc((size_t)512 * 128 * 2);
  ushort_t* w2tl = (ushort_t*)alloc((size_t)512 * 128 * 2);
  ushort_t* w3th = (ushort_t*)alloc((size_t)512 * 256 * 2);
  ushort_t* w3tl = (ushort_t*)alloc((size_t)512 * 256 * 2);
  ushort_t* w4th = (ushort_t*)alloc((size_t)1024 * 256 * 2);
  ushort_t* w4tl = (ushort_t*)alloc((size_t)1024 * 256 * 2);

  const dim3 blk256(256), blk512(512);
  // conv GEMMs: 64M x 128N tile (2x the blocks of the 128-tile version)
  auto mgemm = [&](const ushort_t* Ah, const ushort_t* Al,
                   const ushort_t* Bh, const ushort_t* Bl, const float* bias,
                   int M, int Nn, int K, float* outF) {
    const dim3 grid(Nn / 128, M / 64);
    mfma_gemm64_kernel<<<grid, blk256, 0, stream>>>(
        Ah, Al, Bh, Bl, bias, K, outF, Nn);
  };

  // ---- prep: weights + vp1/vp2 in one dispatch ----
  prep_kernel<<<dim3(6588), blk256, 0, stream>>>(
      w1, w2, w3, w4, cw1, cw2, vertices, sidx1, sidx2,
      w1th, w1tl, w2th, w2tl, w3th, w3tl, w4th, w4tl,
      w1h, w1l, w2h, w2l, vp1, vp2);

  // ---- mega: 3 KNN levels + inline fm0 + both nearest argmins ----
  mega_kernel<<<dim3(6784), blk512, 0, stream>>>(
      vertices, vp1, vp2, dir0, nb1, nb2, nb3, f0h, f0l, near1, near2);

  // ---- level 0 (4096 verts) ----
  mgemm(f0h, f0l, w1th, w1tl, b1, B_ * N0, 256, 128, fbuf);
  conv_combine_kernel<<<dim3(B_ * N0), dim3(128), 0, stream>>>(
      fbuf, nb1, d1, vertices, N0, 128, 1, f1h, f1l);

  // ---- pool 1 -> 1024 (top-4 = first 4 of nb1 rows at sidx1) ----
  pool_kernel<<<dim3((B_ * N1 * 128 + 255) / 256), blk256, 0, stream>>>(
      f1h, f1l, nb1, sidx1, N1, N0, 128, p1h, p1l);

  // ---- level 1 (1024 verts) ----
  mgemm(p1h, p1l, w2th, w2tl, b2, B_ * N1, 512, 128, fbuf);
  conv_combine_kernel<<<dim3(B_ * N1), dim3(256), 0, stream>>>(
      fbuf, nb2, d2, vp1, N1, 256, 1, f2h, f2l);
  mgemm(f2h, f2l, w3th, w3tl, b3, B_ * N1, 512, 256, fbuf);
  conv_combine_kernel<<<dim3(B_ * N1), dim3(256), 0, stream>>>(
      fbuf, nb2, d3, vp1, N1, 256, 1, f3h, f3l);

  // ---- pool 2 -> 256 ----
  pool_kernel<<<dim3((B_ * N2 * 256 + 255) / 256), blk256, 0, stream>>>(
      f3h, f3l, nb2, sidx2, N2, N1, 256, p2h, p2l);

  // ---- level 2 (256 verts) ----
  mgemm(p2h, p2l, w4th, w4tl, b4, B_ * N2, 1024, 256, fbuf);
  conv_combine_kernel<<<dim3(B_ * N2), dim3(512), 0, stream>>>(
      fbuf, nb3, d4, vp2, N2, 512, 0, f4h, f4l);     // no relu on fm_4
  global_max_kernel<<<dim3(B_ * 8), blk256, 0, stream>>>(f4h, f4l, fgh, fgl);

  // ---- head MLP (128x128 tile: big-K, LDS-ratio-optimal) ----
  mfma_gemm_kernel<true, true, true><<<dim3(512 / 128, (B_ * N0) / 128), blk256, 0, stream>>>(
      nullptr, nullptr,
      f0h, f0l, f1h, f1l, f2h, f2l, f3h, f3l, f4h, f4l, fgh, fgl,
      near1, near2, w1h, w1l, cb1, 1792, nullptr, h1h, h1l, 512);
  mfma_gemm_kernel<false, false, true><<<dim3(512 / 128, (B_ * N0) / 128), blk256, 0, stream>>>(
      h1h, h1l,
      nullptr, nullptr, nullptr, nullptr, nullptr, nullptr, nullptr, nullptr,
      nullptr, nullptr, nullptr, nullptr,
      nullptr, nullptr, w2h, w2l, cb2, 512, h2, nullptr, nullptr, 512);
  head_wave_kernel<<<dim3((B_ * N0) / 4), blk256, 0, stream>>>(
      h2, cw3, cb3, (float*)d_out);
}